// Round 7
// baseline (457.145 us; speedup 1.0000x reference)
//
#include <hip/hip_runtime.h>
#include <hip/hip_bf16.h>
#include <cstdint>
#include <type_traits>

#define GLOBAL_AS __attribute__((address_space(1)))
#define LDS_AS    __attribute__((address_space(3)))

typedef short bf16x8 __attribute__((ext_vector_type(8)));
typedef short short8_t __attribute__((ext_vector_type(8)));
typedef float f32x4  __attribute__((ext_vector_type(4)));

static constexpr int E_DIM = 1024;   // hidden
static constexpr int HD = 64;
static constexpr int QKV_STRIDE = 3072;
static constexpr int KDIM = 1024;        // K for both GEMMs
static constexpr int NKH  = KDIM / 32;   // 32 k-halves (phases)

__device__ __forceinline__ float b2f(short s) {
    union { unsigned u; float f; } x;
    x.u = ((unsigned)(unsigned short)s) << 16;
    return x.f;
}
__device__ __forceinline__ short f2b(float f) {
    union { float f; unsigned u; } x; x.f = f;
    unsigned r = x.u + 0x7FFF + ((x.u >> 16) & 1);
    return (short)(r >> 16);
}

// ---------------- fp32 -> bf16 convert ----------------
__global__ __launch_bounds__(256) void k_convert(const float* __restrict__ in,
                                                 short* __restrict__ out, int n4) {
    int i = blockIdx.x * 256 + threadIdx.x;
    if (i >= n4) return;
    float4 v = reinterpret_cast<const float4*>(in)[i];
    short4 o;
    o.x = f2b(v.x); o.y = f2b(v.y); o.z = f2b(v.z); o.w = f2b(v.w);
    reinterpret_cast<short4*>(out)[i] = o;
}

// ---------------- bias concat [bq | bk | bv] ----------
__global__ __launch_bounds__(256) void k_bcat(const float* __restrict__ bq,
                                              const float* __restrict__ bk,
                                              const float* __restrict__ bv,
                                              float* __restrict__ o) {
    int i = blockIdx.x * 256 + threadIdx.x;
    float v = (i < 1024) ? bq[i] : (i < 2048 ? bk[i - 1024] : bv[i - 2048]);
    o[i] = v;
}

// ==== 128x256 bf16 GEMM, 2 blocks/CU (occupancy-first), ring-3 LDS ====
// C[M][N] = A[M][K] * B[N][K]^T + bias. K = KDIM = 1024.
// 512 threads = 8 waves (2M x 4N), per-wave 64x64 output (acc 64 f32 ->
// ~120 unified regs -> 4 waves/SIMD). LDS = 3 x (A 8K + B 16K) = 72 KiB
// -> 2 blocks/CU; co-resident block fills barrier/stall bubbles.
// Ring-3, prefetch depth 2, 3 loads/phase/thread:
//   prologue: stage kh0->R0, kh1->R1 (6 loads); vmcnt(3); barrier.
//   phase h: 8 ds_read from R(h%3); stage kh(h+2)->R((h+2)%3); 16 MFMA
//   (compiler-inserted lgkmcnt); vmcnt(3) retires kh(h+1); ONE barrier.
// Hazards checked: stage target R((h+2)%3) last read at phase h-1, whose
// reads drain (lgkmcnt) before its trailing barrier; consumed region's
// staging retired by previous phase's vmcnt(3)+barrier (cross-wave safe).
template <typename OutT>
__global__ __launch_bounds__(512, 4) void k_gemm128x256(
    const short* __restrict__ A,    // [M][KDIM]
    const short* __restrict__ Bm,   // [N][KDIM]
    const float* __restrict__ bias, // [N]
    OutT* __restrict__ C,           // [M][N]
    int NT_N, int N)
{
    __shared__ short ldsA[3][128 * 32];   // 3 x 8 KiB
    __shared__ short ldsB[3][256 * 32];   // 3 x 16 KiB

    const int tid  = threadIdx.x;
    const int lane = tid & 63;
    const int wv   = tid >> 6;      // 0..7
    const int wr   = wv >> 2;       // 0..1  (M half, 64 rows each)
    const int wc   = wv & 3;        // 0..3  (N quarter, 64 cols each)
    const int frow = lane & 15;
    const int ks   = lane >> 4;     // k-slot 0..3 within k-half

    // bijective XCD swizzle (grid % 8 == 0), n-fastest so neighbors share A-panel
    const int nwg  = gridDim.x;
    const int nper = nwg >> 3;
    const int bid  = blockIdx.x;
    const int swz  = (bid & 7) * nper + (bid >> 3);
    const int m0   = (swz / NT_N) * 128;
    const int n0   = (swz % NT_N) * 256;

    // staging: chunk c -> (row = c>>2, slot = (c&3)^((c>>3)&3)); linear LDS
    // dest, pre-swizzled global source (rule #21).
    const int cA  = tid;                // A: 1 load  (128 rows)
    const int rA  = cA >> 2,  zA  = ((cA & 3) ^ ((cA >> 3) & 3)) * 8;
    const int cB0 = tid, cB1 = tid + 512;   // B: 2 loads (256 rows)
    const int rB0 = cB0 >> 2, zB0 = ((cB0 & 3) ^ ((cB0 >> 3) & 3)) * 8;
    const int rB1 = cB1 >> 2, zB1 = ((cB1 & 3) ^ ((cB1 >> 3) & 3)) * 8;

#define STAGEA(RG, KH) do {                                                        \
    __builtin_amdgcn_global_load_lds(                                              \
        (const GLOBAL_AS short*)(A + (size_t)(m0 + rA) * KDIM + (KH) * 32 + zA),   \
        (LDS_AS short*)&ldsA[RG][cA * 8], 16, 0, 0);                               \
} while (0)
#define STAGEB(RG, KH) do {                                                        \
    __builtin_amdgcn_global_load_lds(                                              \
        (const GLOBAL_AS short*)(Bm + (size_t)(n0 + rB0) * KDIM + (KH) * 32 + zB0),\
        (LDS_AS short*)&ldsB[RG][cB0 * 8], 16, 0, 0);                              \
    __builtin_amdgcn_global_load_lds(                                              \
        (const GLOBAL_AS short*)(Bm + (size_t)(n0 + rB1) * KDIM + (KH) * 32 + zB1),\
        (LDS_AS short*)&ldsB[RG][cB1 * 8], 16, 0, 0);                              \
} while (0)

#define LDA(RG, R) (*reinterpret_cast<const bf16x8*>(                              \
        &ldsA[RG][((R) * 4 + (ks ^ (((R) >> 1) & 3))) * 8]))
#define LDB(RG, R) (*reinterpret_cast<const bf16x8*>(                              \
        &ldsB[RG][((R) * 4 + (ks ^ (((R) >> 1) & 3))) * 8]))

    f32x4 acc[4][4];
    #pragma unroll
    for (int i = 0; i < 4; ++i)
        #pragma unroll
        for (int j = 0; j < 4; ++j)
            acc[i][j] = (f32x4){0.f, 0.f, 0.f, 0.f};

    bf16x8 af[4], bf[4];

// Phase: read frags from region RG, stage khalf S into region RS,
// 16 MFMA, counted vmcnt, single trailing barrier.
#define PHASE(RG, RS, S) do {                                                      \
    _Pragma("unroll")                                                              \
    for (int mi = 0; mi < 4; ++mi)                                                 \
        af[mi] = LDA(RG, wr * 64 + mi * 16 + frow);                                \
    _Pragma("unroll")                                                              \
    for (int ni = 0; ni < 4; ++ni)                                                 \
        bf[ni] = LDB(RG, wc * 64 + ni * 16 + frow);                                \
    STAGEA(RS, S);                                                                 \
    STAGEB(RS, S);                                                                 \
    __builtin_amdgcn_sched_barrier(0);                                             \
    __builtin_amdgcn_s_setprio(1);                                                 \
    _Pragma("unroll")                                                              \
    for (int mi = 0; mi < 4; ++mi)                                                 \
        _Pragma("unroll")                                                          \
        for (int ni = 0; ni < 4; ++ni)                                             \
            acc[mi][ni] = __builtin_amdgcn_mfma_f32_16x16x32_bf16(                 \
                              af[mi], bf[ni], acc[mi][ni], 0, 0, 0);               \
    __builtin_amdgcn_s_setprio(0);                                                 \
    asm volatile("s_waitcnt vmcnt(3)" ::: "memory");                               \
    __builtin_amdgcn_s_barrier();                                                  \
} while (0)

    // prologue: stage kh0->R0, kh1->R1 (6 loads); vmcnt(3) retires kh0; barrier.
    STAGEA(0, 0);  STAGEB(0, 0);
    STAGEA(1, 1);  STAGEB(1, 1);
    asm volatile("s_waitcnt vmcnt(3)" ::: "memory");
    __builtin_amdgcn_s_barrier();

    // 30 phases in groups of 3 (compile-time regions), then 2 peeled (clamped).
    #pragma unroll 1
    for (int hb = 0; hb < 30; hb += 3) {
        PHASE(0, 2, hb + 2);
        PHASE(1, 0, hb + 3);
        PHASE(2, 1, hb + 4);
    }
    PHASE(0, 2, 31);   // phase 30 (stage clamped: dup kh31 -> dead region)
    PHASE(1, 0, 31);   // phase 31

    asm volatile("s_waitcnt vmcnt(0)" ::: "memory");   // drain tail prefetches

    // epilogue: C/D layout col = lane&15, row = (lane>>4)*4 + r
    const int crow = (lane >> 4) * 4;
    const int ccol = lane & 15;
    float bv4[4];
    #pragma unroll
    for (int ni = 0; ni < 4; ++ni)
        bv4[ni] = bias[n0 + wc * 64 + ni * 16 + ccol];
    #pragma unroll
    for (int mi = 0; mi < 4; ++mi) {
        #pragma unroll
        for (int r = 0; r < 4; ++r) {
            const size_t rowg = (size_t)(m0 + wr * 64 + mi * 16 + crow + r) * N;
            #pragma unroll
            for (int ni = 0; ni < 4; ++ni) {
                const int col = n0 + wc * 64 + ni * 16 + ccol;
                float v = acc[mi][ni][r] + bv4[ni];
                if constexpr (std::is_same<OutT, float>::value) {
                    C[rowg + col] = v;
                } else {
                    C[rowg + col] = f2b(v);
                }
            }
        }
    }
#undef PHASE
#undef LDA
#undef LDB
#undef STAGEA
#undef STAGEB
}

// ---------------- per-token head-mixing attention ----------------------
__global__ __launch_bounds__(256) void k_attn(
    const short* __restrict__ QKV, short* __restrict__ O)
{
    __shared__ short Ks[16][1032];
    __shared__ short Vs[16][1032];

    const int tid = threadIdx.x;
    const int tok0 = blockIdx.x * 16;

    for (int i = tid; i < 2048; i += 256) {
        int t = i >> 7;
        int j = i & 127;
        const size_t base = (size_t)(tok0 + t) * QKV_STRIDE;
        *reinterpret_cast<short8_t*>(&Ks[t][j * 8]) =
            *reinterpret_cast<const short8_t*>(&QKV[base + 1024 + j * 8]);
        *reinterpret_cast<short8_t*>(&Vs[t][j * 8]) =
            *reinterpret_cast<const short8_t*>(&QKV[base + 2048 + j * 8]);
    }
    __syncthreads();

    const int tl = tid >> 4;
    const int h  = tid & 15;

    float qf[64];
    const short* qp = QKV + (size_t)(tok0 + tl) * QKV_STRIDE + h * HD;
    #pragma unroll
    for (int i = 0; i < 8; ++i) {
        short8_t v = *reinterpret_cast<const short8_t*>(&qp[i * 8]);
        #pragma unroll
        for (int j = 0; j < 8; ++j) qf[i * 8 + j] = b2f(v[j]);
    }

    float s[16];
    #pragma unroll
    for (int g = 0; g < 16; ++g) {
        float a = 0.f;
        #pragma unroll
        for (int i = 0; i < 8; ++i) {
            short8_t kv = *reinterpret_cast<const short8_t*>(&Ks[tl][g * HD + i * 8]);
            #pragma unroll
            for (int j = 0; j < 8; ++j) a += qf[i * 8 + j] * b2f(kv[j]);
        }
        s[g] = a * 0.125f;
    }
    float mx = s[0];
    #pragma unroll
    for (int g = 1; g < 16; ++g) mx = fmaxf(mx, s[g]);
    float l = 0.f;
    #pragma unroll
    for (int g = 0; g < 16; ++g) { s[g] = __expf(s[g] - mx); l += s[g]; }
    const float inv = 1.f / l;
    #pragma unroll
    for (int g = 0; g < 16; ++g) s[g] *= inv;

    short* op = O + (size_t)(tok0 + tl) * E_DIM + h * HD;
    #pragma unroll
    for (int c = 0; c < 4; ++c) {
        float a[16];
        #pragma unroll
        for (int j = 0; j < 16; ++j) a[j] = 0.f;
        #pragma unroll
        for (int g = 0; g < 16; ++g) {
            short8_t v0 = *reinterpret_cast<const short8_t*>(&Vs[tl][g * HD + c * 16]);
            short8_t v1 = *reinterpret_cast<const short8_t*>(&Vs[tl][g * HD + c * 16 + 8]);
            #pragma unroll
            for (int j = 0; j < 8; ++j) {
                a[j]     += s[g] * b2f(v0[j]);
                a[8 + j] += s[g] * b2f(v1[j]);
            }
        }
        short8_t o0, o1;
        #pragma unroll
        for (int j = 0; j < 8; ++j) { o0[j] = f2b(a[j]); o1[j] = f2b(a[8 + j]); }
        *reinterpret_cast<short8_t*>(&op[c * 16])     = o0;
        *reinterpret_cast<short8_t*>(&op[c * 16 + 8]) = o1;
    }
}

extern "C" void kernel_launch(void* const* d_in, const int* in_sizes, int n_in,
                              void* d_out, int out_size, void* d_ws, size_t ws_size,
                              hipStream_t stream) {
    const float* x  = (const float*)d_in[0];
    const float* Wq = (const float*)d_in[1];
    const float* bq = (const float*)d_in[2];
    const float* Wk = (const float*)d_in[3];
    const float* bk = (const float*)d_in[4];
    const float* Wv = (const float*)d_in[5];
    const float* bv = (const float*)d_in[6];
    const float* Wo = (const float*)d_in[7];
    const float* bo = (const float*)d_in[8];
    float* out = (float*)d_out;

    const int T = in_sizes[0] / E_DIM;      // 32768 tokens
    char* ws = (char*)d_ws;
    const size_t SZ_X    = (size_t)T * E_DIM * 2;
    const size_t SZ_WQKV = (size_t)3 * E_DIM * E_DIM * 2;
    const size_t SZ_W    = (size_t)E_DIM * E_DIM * 2;
    const size_t SZ_B    = 3072 * sizeof(float) + 4096;

    short* xb    = (short*)(ws);
    short* Wqkvb = (short*)(ws + SZ_X);
    short* Wob   = (short*)(ws + SZ_X + SZ_WQKV);
    float* bqkv  = (float*)(ws + SZ_X + SZ_WQKV + SZ_W);
    short* QKVb  = (short*)(ws + SZ_X + SZ_WQKV + SZ_W + SZ_B);
    short* Ab    = xb;   // reuse x-bf16 buffer for attention output

    const int n4x = T * E_DIM / 4;
    const int n4w = E_DIM * E_DIM / 4;
    k_convert<<<dim3((n4x + 255) / 256), dim3(256), 0, stream>>>(x,  xb, n4x);
    k_convert<<<dim3((n4w + 255) / 256), dim3(256), 0, stream>>>(Wq, Wqkvb,                     n4w);
    k_convert<<<dim3((n4w + 255) / 256), dim3(256), 0, stream>>>(Wk, Wqkvb + E_DIM * E_DIM,     n4w);
    k_convert<<<dim3((n4w + 255) / 256), dim3(256), 0, stream>>>(Wv, Wqkvb + 2 * E_DIM * E_DIM, n4w);
    k_convert<<<dim3((n4w + 255) / 256), dim3(256), 0, stream>>>(Wo, Wob, n4w);
    k_bcat<<<dim3(12), dim3(256), 0, stream>>>(bq, bk, bv, bqkv);

    // fused QKV GEMM: [T][3072]
    k_gemm128x256<short><<<dim3((T / 128) * (QKV_STRIDE / 256)), dim3(512), 0, stream>>>(
        xb, Wqkvb, bqkv, QKVb, QKV_STRIDE / 256, QKV_STRIDE);

    k_attn<<<dim3(T / 16), dim3(256), 0, stream>>>(QKVb, Ab);

    // output GEMM: [T][1024] fp32
    k_gemm128x256<float><<<dim3((T / 128) * (E_DIM / 256)), dim3(512), 0, stream>>>(
        Ab, Wob, bo, out, E_DIM / 256, E_DIM);
}

// Round 9
// 411.627 us; speedup vs baseline: 1.1106x; 1.1106x over previous
//
#include <hip/hip_runtime.h>
#include <hip/hip_bf16.h>
#include <cstdint>
#include <type_traits>

#define GLOBAL_AS __attribute__((address_space(1)))
#define LDS_AS    __attribute__((address_space(3)))

typedef short bf16x8 __attribute__((ext_vector_type(8)));
typedef short short8_t __attribute__((ext_vector_type(8)));
typedef float f32x4  __attribute__((ext_vector_type(4)));

static constexpr int E_DIM = 1024;
static constexpr int HD = 64;
static constexpr int QKV_STRIDE = 3072;
static constexpr int KDIM = 1024;        // K for both GEMMs
static constexpr int NTK  = KDIM / 64;   // 16 K-tiles
static constexpr int NIT  = NTK / 2;     // 8 iterations (2 K-tiles each)

__device__ __forceinline__ float b2f(short s) {
    union { unsigned u; float f; } x;
    x.u = ((unsigned)(unsigned short)s) << 16;
    return x.f;
}
__device__ __forceinline__ short f2b(float f) {
    union { float f; unsigned u; } x; x.f = f;
    unsigned r = x.u + 0x7FFF + ((x.u >> 16) & 1);
    return (short)(r >> 16);
}

// ---------------- fp32 -> bf16 convert ----------------
__global__ __launch_bounds__(256) void k_convert(const float* __restrict__ in,
                                                 short* __restrict__ out, int n4) {
    int i = blockIdx.x * 256 + threadIdx.x;
    if (i >= n4) return;
    float4 v = reinterpret_cast<const float4*>(in)[i];
    short4 o;
    o.x = f2b(v.x); o.y = f2b(v.y); o.z = f2b(v.z); o.w = f2b(v.w);
    reinterpret_cast<short4*>(out)[i] = o;
}

// ---------------- bias concat [bq | bk | bv] ----------
__global__ __launch_bounds__(256) void k_bcat(const float* __restrict__ bq,
                                              const float* __restrict__ bk,
                                              const float* __restrict__ bv,
                                              float* __restrict__ o) {
    int i = blockIdx.x * 256 + threadIdx.x;
    float v = (i < 1024) ? bq[i] : (i < 2048 ? bk[i - 1024] : bv[i - 2048]);
    o[i] = v;
}

// ======== 256x256 8-phase bf16 GEMM (m201 structure, fixed lifetimes) ========
// C[M][N] = A[M][K]*B[N][K]^T + bias, K=1024. 512 thr = 8 waves (2M x 4N),
// per-wave C = 128x64. LDS[2buf][2mat][2 row-half][128 rows][64 k] = 128 KiB.
// Register reuse per K-tile (20 ds_read_b128/wave vs 48 in naive):
//   Q0(j0): RD af(rows0-63)+bfA(cols0-31), MM acc[0-3][0-1]
//   Q1(j1): RD bfB(cols32-63),             MM acc[0-3][2-3]
//   Q2(j2): RD af(rows64-127),             MM acc[4-7][0-1]
//   Q3(j3): no reads,                      MM acc[4-7][2-3]
// REGION LIFETIMES (per buf): B-regions last read j1; A-regions last read j2
// (each wave reads its FULL 128-row A-half across Q0+Q2). Stage schedule:
//   j2: B-pair of next tile (after j1 barrier) ; j3: A-pair (after j2 barrier)
//   j6/j7: same for the odd buf. vmcnt(8) at j3/j7 retires exactly the 8
//   loads of the tile consumed next (FIFO: 8 outstanding at j0, +4@j2,
//   +4@j3 -> 16 -> VM8 retires oldest 8). Prologue: tile0(8)+tile1(8),
//   VM8 retires tile0. Tail: clamp to tile15 -> identical-byte dup stages
//   (count-preserving, value-benign).
template <typename OutT>
__global__ __launch_bounds__(512, 2) void k_gemm256(
    const short* __restrict__ A,    // [M][KDIM]
    const short* __restrict__ Bm,   // [N][KDIM]
    const float* __restrict__ bias, // [N]
    OutT* __restrict__ C,           // [M][N]
    int NT_N, int N)
{
    __shared__ short lds[65536];   // [buf]*32768 + [mat]*16384 + [half]*8192

    const int tid  = threadIdx.x;
    const int lane = tid & 63;
    const int wv   = tid >> 6;
    const int wr   = wv >> 2;       // 0..1 M half
    const int wc   = wv & 3;        // 0..3 N quarter
    const int frow = lane & 15;
    const int ks   = lane >> 4;     // k-slot within 32-k
    const int sw   = frow & 7;      // read-side swizzle key
    const int sl0  = ((0 + ks) ^ sw) * 8;   // kk=0 slot offset (shorts)
    const int sl1  = ((4 + ks) ^ sw) * 8;   // kk=1

    // bijective XCD swizzle (grid%8==0), n-fastest (neighbors share A-panel)
    const int nwg = gridDim.x, nper = nwg >> 3, bid = blockIdx.x;
    const int swz = (bid & 7) * nper + (bid >> 3);
    const int m0  = (swz / NT_N) * 256;
    const int n0  = (swz % NT_N) * 256;

    // read bases (shorts, within buf)
    const int ArdBase = wr * 8192;
    const int BrdBase = 16384 + (wc >> 1) * 8192 + (wc & 1) * 4096;

    // staging: thread covers rows srow and srow+64 of a 128-row half
    const int srow = tid >> 3;                       // 0..63
    const int ssl  = ((tid & 7) ^ (srow & 7)) * 8;   // pre-swizzled source slot
    const int sdst = tid * 8;                        // linear LDS dest

#define GLD(SRC, DST) __builtin_amdgcn_global_load_lds(                            \
        (const GLOBAL_AS short*)(SRC), (LDS_AS short*)(DST), 16, 0, 0)
#define STAGE_A(BUF, HALF, T) do {                                                 \
    const short* s_ = A + (size_t)(m0 + (HALF) * 128 + srow) * KDIM + (T) * 64 + ssl; \
    short* d_ = &lds[(BUF) * 32768 + (HALF) * 8192 + sdst];                        \
    GLD(s_, d_);  GLD(s_ + (size_t)64 * KDIM, d_ + 4096);                          \
} while (0)
#define STAGE_B(BUF, HALF, T) do {                                                 \
    const short* s_ = Bm + (size_t)(n0 + (HALF) * 128 + srow) * KDIM + (T) * 64 + ssl; \
    short* d_ = &lds[(BUF) * 32768 + 16384 + (HALF) * 8192 + sdst];                \
    GLD(s_, d_);  GLD(s_ + (size_t)64 * KDIM, d_ + 4096);                          \
} while (0)

#define RD_A(BUF, MIB) do {                                                        \
    _Pragma("unroll")                                                              \
    for (int m_ = 0; m_ < 4; ++m_) {                                               \
        const short* p_ = &lds[(BUF) * 32768 + ArdBase + ((MIB) + m_) * 1024 + frow * 64]; \
        af[m_][0] = *(const bf16x8*)(p_ + sl0);                                    \
        af[m_][1] = *(const bf16x8*)(p_ + sl1);                                    \
    }                                                                              \
} while (0)
#define RD_B(BUF, NIB, BF) do {                                                    \
    _Pragma("unroll")                                                              \
    for (int n_ = 0; n_ < 2; ++n_) {                                               \
        const short* p_ = &lds[(BUF) * 32768 + BrdBase + ((NIB) + n_) * 1024 + frow * 64]; \
        BF[n_][0] = *(const bf16x8*)(p_ + sl0);                                    \
        BF[n_][1] = *(const bf16x8*)(p_ + sl1);                                    \
    }                                                                              \
} while (0)

#define MM(MB, NB, BF) do {                                                        \
    _Pragma("unroll")                                                              \
    for (int m_ = 0; m_ < 4; ++m_)                                                 \
        _Pragma("unroll")                                                          \
        for (int n_ = 0; n_ < 2; ++n_) {                                           \
            acc[(MB)+m_][(NB)+n_] = __builtin_amdgcn_mfma_f32_16x16x32_bf16(       \
                af[m_][0], BF[n_][0], acc[(MB)+m_][(NB)+n_], 0, 0, 0);             \
            acc[(MB)+m_][(NB)+n_] = __builtin_amdgcn_mfma_f32_16x16x32_bf16(       \
                af[m_][1], BF[n_][1], acc[(MB)+m_][(NB)+n_], 0, 0, 0);             \
        }                                                                          \
} while (0)

#define BAR   __builtin_amdgcn_s_barrier()
#define LGKM0 do { asm volatile("s_waitcnt lgkmcnt(0)" ::: "memory");              \
                   __builtin_amdgcn_sched_barrier(0); } while (0)
#define LGKM8 asm volatile("s_waitcnt lgkmcnt(8)" ::: "memory")
#define VM8   asm volatile("s_waitcnt vmcnt(8)" ::: "memory")
#define PRIO1 __builtin_amdgcn_s_setprio(1)
#define PRIO0 __builtin_amdgcn_s_setprio(0)

    f32x4 acc[8][4];
    #pragma unroll
    for (int i = 0; i < 8; ++i)
        #pragma unroll
        for (int j = 0; j < 4; ++j)
            acc[i][j] = (f32x4){0.f, 0.f, 0.f, 0.f};

    bf16x8 af[4][2], bfA[2][2], bfB[2][2];

    // prologue: tile0 full (8 loads) then tile1 B-pair + A-pair (8 loads);
    // VM8 retires exactly tile0; barrier.
    STAGE_A(0, 0, 0);  STAGE_B(0, 0, 0);  STAGE_B(0, 1, 0);  STAGE_A(0, 1, 0);
    STAGE_B(1, 0, 1);  STAGE_B(1, 1, 1);
    STAGE_A(1, 0, 1);  STAGE_A(1, 1, 1);
    VM8;  BAR;

    #pragma unroll 1
    for (int it = 0; it < NIT; ++it) {
        const int tb = (2 * it + 2 <= 15) ? 2 * it + 2 : 15;
        const int tc = (2 * it + 3 <= 15) ? 2 * it + 3 : 15;
        const int bb = tb & 1, bc = tc & 1;

        // ---- K-tile 2it (buf 0) ----
        // j=0 / Q0
        RD_A(0, 0);  RD_B(0, 0, bfA);
        LGKM8;  BAR;  LGKM0;
        PRIO1;  MM(0, 0, bfA);  PRIO0;  BAR;
        // j=1 / Q1
        RD_B(0, 2, bfB);
        BAR;  LGKM0;
        PRIO1;  MM(0, 2, bfB);  PRIO0;  BAR;
        // j=2 / Q2  (B-regions of buf0 free after j1 barrier -> stage B-pair)
        RD_A(0, 4);
        STAGE_B(bb, 0, tb);  STAGE_B(bb, 1, tb);
        BAR;  LGKM0;
        PRIO1;  MM(4, 0, bfA);  PRIO0;  BAR;
        // j=3 / Q3  (A-regions free after j2 barrier -> stage A-pair)
        STAGE_A(bb, 0, tb);  STAGE_A(bb, 1, tb);
        BAR;
        PRIO1;  MM(4, 2, bfB);  PRIO0;
        VM8;  BAR;                    // retires odd tile consumed at j4..j7

        // ---- K-tile 2it+1 (buf 1) ----
        // j=4 / Q0
        RD_A(1, 0);  RD_B(1, 0, bfA);
        LGKM8;  BAR;  LGKM0;
        PRIO1;  MM(0, 0, bfA);  PRIO0;  BAR;
        // j=5 / Q1
        RD_B(1, 2, bfB);
        BAR;  LGKM0;
        PRIO1;  MM(0, 2, bfB);  PRIO0;  BAR;
        // j=6 / Q2
        RD_A(1, 4);
        STAGE_B(bc, 0, tc);  STAGE_B(bc, 1, tc);
        BAR;  LGKM0;
        PRIO1;  MM(4, 0, bfA);  PRIO0;  BAR;
        // j=7 / Q3
        STAGE_A(bc, 0, tc);  STAGE_A(bc, 1, tc);
        BAR;
        PRIO1;  MM(4, 2, bfB);  PRIO0;
        VM8;  BAR;                    // retires even tile consumed next iter
    }

    asm volatile("s_waitcnt vmcnt(0)" ::: "memory");   // drain tail dups

    // epilogue: C/D layout col = lane&15, row = (lane>>4)*4 + r
    const int crow = (lane >> 4) * 4;
    const int ccol = lane & 15;
    float bv4[4];
    #pragma unroll
    for (int ni = 0; ni < 4; ++ni)
        bv4[ni] = bias[n0 + wc * 64 + ni * 16 + ccol];
    #pragma unroll
    for (int mi = 0; mi < 8; ++mi) {
        #pragma unroll
        for (int r = 0; r < 4; ++r) {
            const size_t rowg = (size_t)(m0 + wr * 128 + mi * 16 + crow + r) * N;
            #pragma unroll
            for (int ni = 0; ni < 4; ++ni) {
                const int col = n0 + wc * 64 + ni * 16 + ccol;
                float v = acc[mi][ni][r] + bv4[ni];
                if constexpr (std::is_same<OutT, float>::value) {
                    C[rowg + col] = v;
                } else {
                    C[rowg + col] = f2b(v);
                }
            }
        }
    }
#undef GLD
#undef STAGE_A
#undef STAGE_B
#undef RD_A
#undef RD_B
#undef MM
#undef BAR
#undef LGKM0
#undef LGKM8
#undef VM8
#undef PRIO1
#undef PRIO0
}

// ---------------- per-token head-mixing attention ----------------------
__global__ __launch_bounds__(256) void k_attn(
    const short* __restrict__ QKV, short* __restrict__ O)
{
    __shared__ short Ks[16][1032];
    __shared__ short Vs[16][1032];

    const int tid = threadIdx.x;
    const int tok0 = blockIdx.x * 16;

    for (int i = tid; i < 2048; i += 256) {
        int t = i >> 7;
        int j = i & 127;
        const size_t base = (size_t)(tok0 + t) * QKV_STRIDE;
        *reinterpret_cast<short8_t*>(&Ks[t][j * 8]) =
            *reinterpret_cast<const short8_t*>(&QKV[base + 1024 + j * 8]);
        *reinterpret_cast<short8_t*>(&Vs[t][j * 8]) =
            *reinterpret_cast<const short8_t*>(&QKV[base + 2048 + j * 8]);
    }
    __syncthreads();

    const int tl = tid >> 4;
    const int h  = tid & 15;

    float qf[64];
    const short* qp = QKV + (size_t)(tok0 + tl) * QKV_STRIDE + h * HD;
    #pragma unroll
    for (int i = 0; i < 8; ++i) {
        short8_t v = *reinterpret_cast<const short8_t*>(&qp[i * 8]);
        #pragma unroll
        for (int j = 0; j < 8; ++j) qf[i * 8 + j] = b2f(v[j]);
    }

    float s[16];
    #pragma unroll
    for (int g = 0; g < 16; ++g) {
        float a = 0.f;
        #pragma unroll
        for (int i = 0; i < 8; ++i) {
            short8_t kv = *reinterpret_cast<const short8_t*>(&Ks[tl][g * HD + i * 8]);
            #pragma unroll
            for (int j = 0; j < 8; ++j) a += qf[i * 8 + j] * b2f(kv[j]);
        }
        s[g] = a * 0.125f;
    }
    float mx = s[0];
    #pragma unroll
    for (int g = 1; g < 16; ++g) mx = fmaxf(mx, s[g]);
    float l = 0.f;
    #pragma unroll
    for (int g = 0; g < 16; ++g) { s[g] = __expf(s[g] - mx); l += s[g]; }
    const float inv = 1.f / l;
    #pragma unroll
    for (int g = 0; g < 16; ++g) s[g] *= inv;

    short* op = O + (size_t)(tok0 + tl) * E_DIM + h * HD;
    #pragma unroll
    for (int c = 0; c < 4; ++c) {
        float a[16];
        #pragma unroll
        for (int j = 0; j < 16; ++j) a[j] = 0.f;
        #pragma unroll
        for (int g = 0; g < 16; ++g) {
            short8_t v0 = *reinterpret_cast<const short8_t*>(&Vs[tl][g * HD + c * 16]);
            short8_t v1 = *reinterpret_cast<const short8_t*>(&Vs[tl][g * HD + c * 16 + 8]);
            #pragma unroll
            for (int j = 0; j < 8; ++j) {
                a[j]     += s[g] * b2f(v0[j]);
                a[8 + j] += s[g] * b2f(v1[j]);
            }
        }
        short8_t o0, o1;
        #pragma unroll
        for (int j = 0; j < 8; ++j) { o0[j] = f2b(a[j]); o1[j] = f2b(a[8 + j]); }
        *reinterpret_cast<short8_t*>(&op[c * 16])     = o0;
        *reinterpret_cast<short8_t*>(&op[c * 16 + 8]) = o1;
    }
}

extern "C" void kernel_launch(void* const* d_in, const int* in_sizes, int n_in,
                              void* d_out, int out_size, void* d_ws, size_t ws_size,
                              hipStream_t stream) {
    const float* x  = (const float*)d_in[0];
    const float* Wq = (const float*)d_in[1];
    const float* bq = (const float*)d_in[2];
    const float* Wk = (const float*)d_in[3];
    const float* bk = (const float*)d_in[4];
    const float* Wv = (const float*)d_in[5];
    const float* bv = (const float*)d_in[6];
    const float* Wo = (const float*)d_in[7];
    const float* bo = (const float*)d_in[8];
    float* out = (float*)d_out;

    const int T = in_sizes[0] / E_DIM;      // 32768 tokens
    char* ws = (char*)d_ws;
    const size_t SZ_X    = (size_t)T * E_DIM * 2;
    const size_t SZ_WQKV = (size_t)3 * E_DIM * E_DIM * 2;
    const size_t SZ_W    = (size_t)E_DIM * E_DIM * 2;
    const size_t SZ_B    = 3072 * sizeof(float) + 4096;

    short* xb    = (short*)(ws);
    short* Wqkvb = (short*)(ws + SZ_X);
    short* Wob   = (short*)(ws + SZ_X + SZ_WQKV);
    float* bqkv  = (float*)(ws + SZ_X + SZ_WQKV + SZ_W);
    short* QKVb  = (short*)(ws + SZ_X + SZ_WQKV + SZ_W + SZ_B);
    short* Ab    = xb;   // reuse x-bf16 buffer for attention output

    const int n4x = T * E_DIM / 4;
    const int n4w = E_DIM * E_DIM / 4;
    k_convert<<<dim3((n4x + 255) / 256), dim3(256), 0, stream>>>(x,  xb, n4x);
    k_convert<<<dim3((n4w + 255) / 256), dim3(256), 0, stream>>>(Wq, Wqkvb,                     n4w);
    k_convert<<<dim3((n4w + 255) / 256), dim3(256), 0, stream>>>(Wk, Wqkvb + E_DIM * E_DIM,     n4w);
    k_convert<<<dim3((n4w + 255) / 256), dim3(256), 0, stream>>>(Wv, Wqkvb + 2 * E_DIM * E_DIM, n4w);
    k_convert<<<dim3((n4w + 255) / 256), dim3(256), 0, stream>>>(Wo, Wob, n4w);
    k_bcat<<<dim3(12), dim3(256), 0, stream>>>(bq, bk, bv, bqkv);

    // fused QKV GEMM: [T][3072]
    k_gemm256<short><<<dim3((T / 256) * (QKV_STRIDE / 256)), dim3(512), 0, stream>>>(
        xb, Wqkvb, bqkv, QKVb, QKV_STRIDE / 256, QKV_STRIDE);

    k_attn<<<dim3(T / 16), dim3(256), 0, stream>>>(QKVb, Ab);

    // output GEMM: [T][1024] fp32
    k_gemm256<float><<<dim3((T / 256) * (E_DIM / 256)), dim3(512), 0, stream>>>(
        Ab, Wob, bo, out, E_DIM / 256, E_DIM);
}

// Round 10
// 407.625 us; speedup vs baseline: 1.1215x; 1.0098x over previous
//
#include <hip/hip_runtime.h>
#include <hip/hip_bf16.h>
#include <cstdint>
#include <type_traits>

#define GLOBAL_AS __attribute__((address_space(1)))
#define LDS_AS    __attribute__((address_space(3)))

typedef short bf16x8 __attribute__((ext_vector_type(8)));
typedef short short8_t __attribute__((ext_vector_type(8)));
typedef float f32x4  __attribute__((ext_vector_type(4)));

static constexpr int E_DIM = 1024;
static constexpr int HD = 64;
static constexpr int QKV_STRIDE = 3072;
static constexpr int KDIM = 1024;        // K for both GEMMs
static constexpr int NTK  = KDIM / 64;   // 16 K-tiles
static constexpr int NIT  = NTK / 2;     // 8 iterations (2 K-tiles each)

__device__ __forceinline__ float b2f(short s) {
    union { unsigned u; float f; } x;
    x.u = ((unsigned)(unsigned short)s) << 16;
    return x.f;
}
__device__ __forceinline__ short f2b(float f) {
    union { float f; unsigned u; } x; x.f = f;
    unsigned r = x.u + 0x7FFF + ((x.u >> 16) & 1);
    return (short)(r >> 16);
}

// ---- fused prep: x->bf16, Wq/Wk/Wv->Wqkvb, Wo->Wob, bias concat ----
__global__ __launch_bounds__(256) void k_prep(
    const float* __restrict__ x,
    const float* __restrict__ Wq, const float* __restrict__ Wk,
    const float* __restrict__ Wv, const float* __restrict__ Wo,
    const float* __restrict__ bq, const float* __restrict__ bk,
    const float* __restrict__ bv,
    short* __restrict__ xb, short* __restrict__ Wqkvb, short* __restrict__ Wob,
    float* __restrict__ bqkv, int n4x, int n4w)
{
    int i = blockIdx.x * 256 + threadIdx.x;
    const float* src;
    short* dst;
    int j;
    if (i < n4x)                       { src = x;  dst = xb;                  j = i; }
    else if (i < n4x + n4w)            { src = Wq; dst = Wqkvb;               j = i - n4x; }
    else if (i < n4x + 2 * n4w)        { src = Wk; dst = Wqkvb + 4 * n4w;     j = i - n4x - n4w; }
    else if (i < n4x + 3 * n4w)        { src = Wv; dst = Wqkvb + 8 * n4w;     j = i - n4x - 2 * n4w; }
    else if (i < n4x + 4 * n4w)        { src = Wo; dst = Wob;                 j = i - n4x - 3 * n4w; }
    else {
        int b = i - (n4x + 4 * n4w);   // 0..767 -> bias element group of 4
        if (b < 768) {
            #pragma unroll
            for (int e = 0; e < 4; ++e) {
                int idx = b * 4 + e;
                float v = (idx < 1024) ? bq[idx] : (idx < 2048 ? bk[idx - 1024] : bv[idx - 2048]);
                bqkv[idx] = v;
            }
        }
        return;
    }
    float4 v = reinterpret_cast<const float4*>(src)[j];
    short4 o;
    o.x = f2b(v.x); o.y = f2b(v.y); o.z = f2b(v.z); o.w = f2b(v.w);
    reinterpret_cast<short4*>(dst)[j] = o;
}

// ======== 256x256 8-phase bf16 GEMM (R9 protocol, compiler-managed lgkm) ====
// Identical region lifetimes / stage schedule / vmcnt(8) protocol as R9
// (proven correct). Delta: NO explicit lgkmcnt drains — every ds_read is
// consumed by an MFMA in the same phase, so the register data-dependence
// forces the exact hardware wait (compiler emits fine-grained lgkmcnt(N)).
// sched_barrier(0) immediately AFTER each s_barrier pins the phase boundary:
// next-phase ds_reads can't hoist above the barrier, register-only MFMAs
// can't hoist across it (rule #18), pre-barrier stages can't sink below.
template <typename OutT>
__global__ __launch_bounds__(512, 2) void k_gemm256(
    const short* __restrict__ A,    // [M][KDIM]
    const short* __restrict__ Bm,   // [N][KDIM]
    const float* __restrict__ bias, // [N]
    OutT* __restrict__ C,           // [M][N]
    int NT_N, int N)
{
    __shared__ short lds[65536];   // [buf]*32768 + [mat]*16384 + [half]*8192

    const int tid  = threadIdx.x;
    const int lane = tid & 63;
    const int wv   = tid >> 6;
    const int wr   = wv >> 2;       // 0..1 M half
    const int wc   = wv & 3;        // 0..3 N quarter
    const int frow = lane & 15;
    const int ks   = lane >> 4;     // k-slot within 32-k
    const int sw   = frow & 7;      // read-side swizzle key
    const int sl0  = ((0 + ks) ^ sw) * 8;   // kk=0 slot offset (shorts)
    const int sl1  = ((4 + ks) ^ sw) * 8;   // kk=1

    // bijective XCD swizzle (grid%8==0), n-fastest (neighbors share A-panel)
    const int nwg = gridDim.x, nper = nwg >> 3, bid = blockIdx.x;
    const int swz = (bid & 7) * nper + (bid >> 3);
    const int m0  = (swz / NT_N) * 256;
    const int n0  = (swz % NT_N) * 256;

    // read bases (shorts, within buf)
    const int ArdBase = wr * 8192;
    const int BrdBase = 16384 + (wc >> 1) * 8192 + (wc & 1) * 4096;

    // staging: thread covers rows srow and srow+64 of a 128-row half
    const int srow = tid >> 3;                       // 0..63
    const int ssl  = ((tid & 7) ^ (srow & 7)) * 8;   // pre-swizzled source slot
    const int sdst = tid * 8;                        // linear LDS dest

#define GLD(SRC, DST) __builtin_amdgcn_global_load_lds(                            \
        (const GLOBAL_AS short*)(SRC), (LDS_AS short*)(DST), 16, 0, 0)
#define STAGE_A(BUF, HALF, T) do {                                                 \
    const short* s_ = A + (size_t)(m0 + (HALF) * 128 + srow) * KDIM + (T) * 64 + ssl; \
    short* d_ = &lds[(BUF) * 32768 + (HALF) * 8192 + sdst];                        \
    GLD(s_, d_);  GLD(s_ + (size_t)64 * KDIM, d_ + 4096);                          \
} while (0)
#define STAGE_B(BUF, HALF, T) do {                                                 \
    const short* s_ = Bm + (size_t)(n0 + (HALF) * 128 + srow) * KDIM + (T) * 64 + ssl; \
    short* d_ = &lds[(BUF) * 32768 + 16384 + (HALF) * 8192 + sdst];                \
    GLD(s_, d_);  GLD(s_ + (size_t)64 * KDIM, d_ + 4096);                          \
} while (0)

#define RD_A(BUF, MIB) do {                                                        \
    _Pragma("unroll")                                                              \
    for (int m_ = 0; m_ < 4; ++m_) {                                               \
        const short* p_ = &lds[(BUF) * 32768 + ArdBase + ((MIB) + m_) * 1024 + frow * 64]; \
        af[m_][0] = *(const bf16x8*)(p_ + sl0);                                    \
        af[m_][1] = *(const bf16x8*)(p_ + sl1);                                    \
    }                                                                              \
} while (0)
#define RD_B(BUF, NIB, BF) do {                                                    \
    _Pragma("unroll")                                                              \
    for (int n_ = 0; n_ < 2; ++n_) {                                               \
        const short* p_ = &lds[(BUF) * 32768 + BrdBase + ((NIB) + n_) * 1024 + frow * 64]; \
        BF[n_][0] = *(const bf16x8*)(p_ + sl0);                                    \
        BF[n_][1] = *(const bf16x8*)(p_ + sl1);                                    \
    }                                                                              \
} while (0)

#define MM(MB, NB, BF) do {                                                        \
    _Pragma("unroll")                                                              \
    for (int m_ = 0; m_ < 4; ++m_)                                                 \
        _Pragma("unroll")                                                          \
        for (int n_ = 0; n_ < 2; ++n_) {                                           \
            acc[(MB)+m_][(NB)+n_] = __builtin_amdgcn_mfma_f32_16x16x32_bf16(       \
                af[m_][0], BF[n_][0], acc[(MB)+m_][(NB)+n_], 0, 0, 0);             \
            acc[(MB)+m_][(NB)+n_] = __builtin_amdgcn_mfma_f32_16x16x32_bf16(       \
                af[m_][1], BF[n_][1], acc[(MB)+m_][(NB)+n_], 0, 0, 0);             \
        }                                                                          \
} while (0)

#define BAR   do { __builtin_amdgcn_s_barrier();                                   \
                   __builtin_amdgcn_sched_barrier(0); } while (0)
#define VM8   asm volatile("s_waitcnt vmcnt(8)" ::: "memory")
#define PRIO1 __builtin_amdgcn_s_setprio(1)
#define PRIO0 __builtin_amdgcn_s_setprio(0)

    f32x4 acc[8][4];
    #pragma unroll
    for (int i = 0; i < 8; ++i)
        #pragma unroll
        for (int j = 0; j < 4; ++j)
            acc[i][j] = (f32x4){0.f, 0.f, 0.f, 0.f};

    bf16x8 af[4][2], bfA[2][2], bfB[2][2];

    // prologue: tile0 full (8 loads) then tile1 B-pair + A-pair (8 loads);
    // VM8 retires exactly tile0; barrier.
    STAGE_A(0, 0, 0);  STAGE_B(0, 0, 0);  STAGE_B(0, 1, 0);  STAGE_A(0, 1, 0);
    STAGE_B(1, 0, 1);  STAGE_B(1, 1, 1);
    STAGE_A(1, 0, 1);  STAGE_A(1, 1, 1);
    VM8;  BAR;

    #pragma unroll 1
    for (int it = 0; it < NIT; ++it) {
        const int tb = (2 * it + 2 <= 15) ? 2 * it + 2 : 15;
        const int tc = (2 * it + 3 <= 15) ? 2 * it + 3 : 15;
        const int bb = tb & 1, bc = tc & 1;

        // ---- K-tile 2it (buf 0) ----
        // j=0 / Q0
        RD_A(0, 0);  RD_B(0, 0, bfA);
        BAR;
        PRIO1;  MM(0, 0, bfA);  PRIO0;  BAR;
        // j=1 / Q1
        RD_B(0, 2, bfB);
        BAR;
        PRIO1;  MM(0, 2, bfB);  PRIO0;  BAR;
        // j=2 / Q2  (B-regions of buf0 free after j1 barrier -> stage B-pair)
        RD_A(0, 4);
        STAGE_B(bb, 0, tb);  STAGE_B(bb, 1, tb);
        BAR;
        PRIO1;  MM(4, 0, bfA);  PRIO0;  BAR;
        // j=3 / Q3  (A-regions free after j2 barrier -> stage A-pair)
        STAGE_A(bb, 0, tb);  STAGE_A(bb, 1, tb);
        BAR;
        PRIO1;  MM(4, 2, bfB);  PRIO0;
        VM8;  BAR;                    // retires odd tile consumed at j4..j7

        // ---- K-tile 2it+1 (buf 1) ----
        // j=4 / Q0
        RD_A(1, 0);  RD_B(1, 0, bfA);
        BAR;
        PRIO1;  MM(0, 0, bfA);  PRIO0;  BAR;
        // j=5 / Q1
        RD_B(1, 2, bfB);
        BAR;
        PRIO1;  MM(0, 2, bfB);  PRIO0;  BAR;
        // j=6 / Q2
        RD_A(1, 4);
        STAGE_B(bc, 0, tc);  STAGE_B(bc, 1, tc);
        BAR;
        PRIO1;  MM(4, 0, bfA);  PRIO0;  BAR;
        // j=7 / Q3
        STAGE_A(bc, 0, tc);  STAGE_A(bc, 1, tc);
        BAR;
        PRIO1;  MM(4, 2, bfB);  PRIO0;
        VM8;  BAR;                    // retires even tile consumed next iter
    }

    asm volatile("s_waitcnt vmcnt(0)" ::: "memory");   // drain tail dups

    // epilogue: C/D layout col = lane&15, row = (lane>>4)*4 + r
    const int crow = (lane >> 4) * 4;
    const int ccol = lane & 15;
    float bv4[4];
    #pragma unroll
    for (int ni = 0; ni < 4; ++ni)
        bv4[ni] = bias[n0 + wc * 64 + ni * 16 + ccol];
    #pragma unroll
    for (int mi = 0; mi < 8; ++mi) {
        #pragma unroll
        for (int r = 0; r < 4; ++r) {
            const size_t rowg = (size_t)(m0 + wr * 128 + mi * 16 + crow + r) * N;
            #pragma unroll
            for (int ni = 0; ni < 4; ++ni) {
                const int col = n0 + wc * 64 + ni * 16 + ccol;
                float v = acc[mi][ni][r] + bv4[ni];
                if constexpr (std::is_same<OutT, float>::value) {
                    C[rowg + col] = v;
                } else {
                    C[rowg + col] = f2b(v);
                }
            }
        }
    }
#undef GLD
#undef STAGE_A
#undef STAGE_B
#undef RD_A
#undef RD_B
#undef MM
#undef BAR
#undef VM8
#undef PRIO1
#undef PRIO0
}

// ---------------- per-token head-mixing attention ----------------------
__global__ __launch_bounds__(256) void k_attn(
    const short* __restrict__ QKV, short* __restrict__ O)
{
    __shared__ short Ks[16][1032];
    __shared__ short Vs[16][1032];

    const int tid = threadIdx.x;
    const int tok0 = blockIdx.x * 16;

    for (int i = tid; i < 2048; i += 256) {
        int t = i >> 7;
        int j = i & 127;
        const size_t base = (size_t)(tok0 + t) * QKV_STRIDE;
        *reinterpret_cast<short8_t*>(&Ks[t][j * 8]) =
            *reinterpret_cast<const short8_t*>(&QKV[base + 1024 + j * 8]);
        *reinterpret_cast<short8_t*>(&Vs[t][j * 8]) =
            *reinterpret_cast<const short8_t*>(&QKV[base + 2048 + j * 8]);
    }
    __syncthreads();

    const int tl = tid >> 4;
    const int h  = tid & 15;

    float qf[64];
    const short* qp = QKV + (size_t)(tok0 + tl) * QKV_STRIDE + h * HD;
    #pragma unroll
    for (int i = 0; i < 8; ++i) {
        short8_t v = *reinterpret_cast<const short8_t*>(&qp[i * 8]);
        #pragma unroll
        for (int j = 0; j < 8; ++j) qf[i * 8 + j] = b2f(v[j]);
    }

    float s[16];
    #pragma unroll
    for (int g = 0; g < 16; ++g) {
        float a = 0.f;
        #pragma unroll
        for (int i = 0; i < 8; ++i) {
            short8_t kv = *reinterpret_cast<const short8_t*>(&Ks[tl][g * HD + i * 8]);
            #pragma unroll
            for (int j = 0; j < 8; ++j) a += qf[i * 8 + j] * b2f(kv[j]);
        }
        s[g] = a * 0.125f;
    }
    float mx = s[0];
    #pragma unroll
    for (int g = 1; g < 16; ++g) mx = fmaxf(mx, s[g]);
    float l = 0.f;
    #pragma unroll
    for (int g = 0; g < 16; ++g) { s[g] = __expf(s[g] - mx); l += s[g]; }
    const float inv = 1.f / l;
    #pragma unroll
    for (int g = 0; g < 16; ++g) s[g] *= inv;

    short* op = O + (size_t)(tok0 + tl) * E_DIM + h * HD;
    #pragma unroll
    for (int c = 0; c < 4; ++c) {
        float a[16];
        #pragma unroll
        for (int j = 0; j < 16; ++j) a[j] = 0.f;
        #pragma unroll
        for (int g = 0; g < 16; ++g) {
            short8_t v0 = *reinterpret_cast<const short8_t*>(&Vs[tl][g * HD + c * 16]);
            short8_t v1 = *reinterpret_cast<const short8_t*>(&Vs[tl][g * HD + c * 16 + 8]);
            #pragma unroll
            for (int j = 0; j < 8; ++j) {
                a[j]     += s[g] * b2f(v0[j]);
                a[8 + j] += s[g] * b2f(v1[j]);
            }
        }
        short8_t o0, o1;
        #pragma unroll
        for (int j = 0; j < 8; ++j) { o0[j] = f2b(a[j]); o1[j] = f2b(a[8 + j]); }
        *reinterpret_cast<short8_t*>(&op[c * 16])     = o0;
        *reinterpret_cast<short8_t*>(&op[c * 16 + 8]) = o1;
    }
}

extern "C" void kernel_launch(void* const* d_in, const int* in_sizes, int n_in,
                              void* d_out, int out_size, void* d_ws, size_t ws_size,
                              hipStream_t stream) {
    const float* x  = (const float*)d_in[0];
    const float* Wq = (const float*)d_in[1];
    const float* bq = (const float*)d_in[2];
    const float* Wk = (const float*)d_in[3];
    const float* bk = (const float*)d_in[4];
    const float* Wv = (const float*)d_in[5];
    const float* bv = (const float*)d_in[6];
    const float* Wo = (const float*)d_in[7];
    const float* bo = (const float*)d_in[8];
    float* out = (float*)d_out;

    const int T = in_sizes[0] / E_DIM;      // 32768 tokens
    char* ws = (char*)d_ws;
    const size_t SZ_X    = (size_t)T * E_DIM * 2;
    const size_t SZ_WQKV = (size_t)3 * E_DIM * E_DIM * 2;
    const size_t SZ_W    = (size_t)E_DIM * E_DIM * 2;
    const size_t SZ_B    = 3072 * sizeof(float) + 4096;

    short* xb    = (short*)(ws);
    short* Wqkvb = (short*)(ws + SZ_X);
    short* Wob   = (short*)(ws + SZ_X + SZ_WQKV);
    float* bqkv  = (float*)(ws + SZ_X + SZ_WQKV + SZ_W);
    short* QKVb  = (short*)(ws + SZ_X + SZ_WQKV + SZ_W + SZ_B);
    short* Ab    = xb;   // reuse x-bf16 buffer for attention output

    const int n4x = T * E_DIM / 4;          // 8M float4
    const int n4w = E_DIM * E_DIM / 4;      // 256K float4
    const int nprep = n4x + 4 * n4w + 768;
    k_prep<<<dim3((nprep + 255) / 256), dim3(256), 0, stream>>>(
        x, Wq, Wk, Wv, Wo, bq, bk, bv, xb, Wqkvb, Wob, bqkv, n4x, n4w);

    // fused QKV GEMM: [T][3072]
    k_gemm256<short><<<dim3((T / 256) * (QKV_STRIDE / 256)), dim3(512), 0, stream>>>(
        xb, Wqkvb, bqkv, QKVb, QKV_STRIDE / 256, QKV_STRIDE);

    k_attn<<<dim3(T / 16), dim3(256), 0, stream>>>(QKVb, Ab);

    // output GEMM: [T][1024] fp32
    k_gemm256<float><<<dim3((T / 256) * (E_DIM / 256)), dim3(512), 0, stream>>>(
        Ab, Wob, bo, out, E_DIM / 256, E_DIM);
}

// Round 11
// 393.004 us; speedup vs baseline: 1.1632x; 1.0372x over previous
//
#include <hip/hip_runtime.h>
#include <hip/hip_bf16.h>
#include <cstdint>
#include <type_traits>

#define GLOBAL_AS __attribute__((address_space(1)))
#define LDS_AS    __attribute__((address_space(3)))

typedef short bf16x8 __attribute__((ext_vector_type(8)));
typedef short short8_t __attribute__((ext_vector_type(8)));
typedef float f32x4  __attribute__((ext_vector_type(4)));

static constexpr int E_DIM = 1024;
static constexpr int HD = 64;
static constexpr int QKV_STRIDE = 3072;
static constexpr int KDIM = 1024;        // K for both GEMMs
static constexpr int NTK  = KDIM / 64;   // 16 K-tiles
static constexpr int NIT  = NTK / 2;     // 8 iterations (2 K-tiles each)

__device__ __forceinline__ float b2f(short s) {
    union { unsigned u; float f; } x;
    x.u = ((unsigned)(unsigned short)s) << 16;
    return x.f;
}
__device__ __forceinline__ short f2b(float f) {
    union { float f; unsigned u; } x; x.f = f;
    unsigned r = x.u + 0x7FFF + ((x.u >> 16) & 1);
    return (short)(r >> 16);
}

// ---- fused prep: x->bf16, Wq/Wk/Wv->Wqkvb, Wo->Wob, bias concat ----
__global__ __launch_bounds__(256) void k_prep(
    const float* __restrict__ x,
    const float* __restrict__ Wq, const float* __restrict__ Wk,
    const float* __restrict__ Wv, const float* __restrict__ Wo,
    const float* __restrict__ bq, const float* __restrict__ bk,
    const float* __restrict__ bv,
    short* __restrict__ xb, short* __restrict__ Wqkvb, short* __restrict__ Wob,
    float* __restrict__ bqkv, int n4x, int n4w)
{
    int i = blockIdx.x * 256 + threadIdx.x;
    const float* src;
    short* dst;
    int j;
    if (i < n4x)                       { src = x;  dst = xb;                  j = i; }
    else if (i < n4x + n4w)            { src = Wq; dst = Wqkvb;               j = i - n4x; }
    else if (i < n4x + 2 * n4w)        { src = Wk; dst = Wqkvb + 4 * n4w;     j = i - n4x - n4w; }
    else if (i < n4x + 3 * n4w)        { src = Wv; dst = Wqkvb + 8 * n4w;     j = i - n4x - 2 * n4w; }
    else if (i < n4x + 4 * n4w)        { src = Wo; dst = Wob;                 j = i - n4x - 3 * n4w; }
    else {
        int b = i - (n4x + 4 * n4w);
        if (b < 768) {
            #pragma unroll
            for (int e = 0; e < 4; ++e) {
                int idx = b * 4 + e;
                float v = (idx < 1024) ? bq[idx] : (idx < 2048 ? bk[idx - 1024] : bv[idx - 2048]);
                bqkv[idx] = v;
            }
        }
        return;
    }
    float4 v = reinterpret_cast<const float4*>(src)[j];
    short4 o;
    o.x = f2b(v.x); o.y = f2b(v.y); o.z = f2b(v.z); o.w = f2b(v.w);
    reinterpret_cast<short4*>(dst)[j] = o;
}

// ======== 256x256 8-phase bf16 GEMM — m201 fence discipline ========
// R9/R10 region lifetimes + ring protocol (proven), with:
//  * plain s_barrier builtins (NO sched_barrier pins, NO memory-clobber lgkm)
//  * smooth staging: exactly one region-half (2 gload_lds/thread) per phase:
//      j0: t_{2it+1}-A0   j1: t_{2it+1}-A1   (buf1-A free since prev j6)
//      j2: t_{2it+2}-B0   j3: t_{2it+2}-B1   (buf0-B free after j1)
//      j4: t_{2it+2}-A0   j5: t_{2it+2}-A1   (buf0-A free after j2)
//      j6: t_{2it+3}-B0   j7: t_{2it+3}-B1   (buf1-B free after j5)
//  * vmcnt(4) ("memory") at end of j3 / j7: FIFO retires exactly the 8 loads
//    of the tile consumed next; youngest retired has 2-phase slack (~2700cyc).
//  * prologue: t0 full + t1-B = 12 loads; vmcnt(4) retires t0.
//  * tail: stage tiles clamp to 15 -> dup stages into dead regions (benign).
template <typename OutT>
__global__ __launch_bounds__(512, 2) void k_gemm256(
    const short* __restrict__ A,    // [M][KDIM]
    const short* __restrict__ Bm,   // [N][KDIM]
    const float* __restrict__ bias, // [N]
    OutT* __restrict__ C,           // [M][N]
    int NT_N, int N)
{
    __shared__ short lds[65536];   // [buf]*32768 + [mat]*16384 + [half]*8192

    const int tid  = threadIdx.x;
    const int lane = tid & 63;
    const int wv   = tid >> 6;
    const int wr   = wv >> 2;       // 0..1 M half
    const int wc   = wv & 3;        // 0..3 N quarter
    const int frow = lane & 15;
    const int ks   = lane >> 4;     // k-slot within 32-k
    const int sw   = frow & 7;      // read-side swizzle key
    const int sl0  = ((0 + ks) ^ sw) * 8;   // kk=0 slot offset (shorts)
    const int sl1  = ((4 + ks) ^ sw) * 8;   // kk=1

    // bijective XCD swizzle (grid%8==0), n-fastest (neighbors share A-panel)
    const int nwg = gridDim.x, nper = nwg >> 3, bid = blockIdx.x;
    const int swz = (bid & 7) * nper + (bid >> 3);
    const int m0  = (swz / NT_N) * 256;
    const int n0  = (swz % NT_N) * 256;

    // read bases (shorts, within buf)
    const int ArdBase = wr * 8192;
    const int BrdBase = 16384 + (wc >> 1) * 8192 + (wc & 1) * 4096;

    // staging: thread covers rows srow and srow+64 of a 128-row half
    const int srow = tid >> 3;                       // 0..63
    const int ssl  = ((tid & 7) ^ (srow & 7)) * 8;   // pre-swizzled source slot
    const int sdst = tid * 8;                        // linear LDS dest

#define GLD(SRC, DST) __builtin_amdgcn_global_load_lds(                            \
        (const GLOBAL_AS short*)(SRC), (LDS_AS short*)(DST), 16, 0, 0)
#define STAGE_A(BUF, HALF, T) do {                                                 \
    const short* s_ = A + (size_t)(m0 + (HALF) * 128 + srow) * KDIM + (T) * 64 + ssl; \
    short* d_ = &lds[(BUF) * 32768 + (HALF) * 8192 + sdst];                        \
    GLD(s_, d_);  GLD(s_ + (size_t)64 * KDIM, d_ + 4096);                          \
} while (0)
#define STAGE_B(BUF, HALF, T) do {                                                 \
    const short* s_ = Bm + (size_t)(n0 + (HALF) * 128 + srow) * KDIM + (T) * 64 + ssl; \
    short* d_ = &lds[(BUF) * 32768 + 16384 + (HALF) * 8192 + sdst];                \
    GLD(s_, d_);  GLD(s_ + (size_t)64 * KDIM, d_ + 4096);                          \
} while (0)

#define RD_A(BUF, MIB) do {                                                        \
    _Pragma("unroll")                                                              \
    for (int m_ = 0; m_ < 4; ++m_) {                                               \
        const short* p_ = &lds[(BUF) * 32768 + ArdBase + ((MIB) + m_) * 1024 + frow * 64]; \
        af[m_][0] = *(const bf16x8*)(p_ + sl0);                                    \
        af[m_][1] = *(const bf16x8*)(p_ + sl1);                                    \
    }                                                                              \
} while (0)
#define RD_B(BUF, NIB, BF) do {                                                    \
    _Pragma("unroll")                                                              \
    for (int n_ = 0; n_ < 2; ++n_) {                                               \
        const short* p_ = &lds[(BUF) * 32768 + BrdBase + ((NIB) + n_) * 1024 + frow * 64]; \
        BF[n_][0] = *(const bf16x8*)(p_ + sl0);                                    \
        BF[n_][1] = *(const bf16x8*)(p_ + sl1);                                    \
    }                                                                              \
} while (0)

#define MM(MB, NB, BF) do {                                                        \
    _Pragma("unroll")                                                              \
    for (int m_ = 0; m_ < 4; ++m_)                                                 \
        _Pragma("unroll")                                                          \
        for (int n_ = 0; n_ < 2; ++n_) {                                           \
            acc[(MB)+m_][(NB)+n_] = __builtin_amdgcn_mfma_f32_16x16x32_bf16(       \
                af[m_][0], BF[n_][0], acc[(MB)+m_][(NB)+n_], 0, 0, 0);             \
            acc[(MB)+m_][(NB)+n_] = __builtin_amdgcn_mfma_f32_16x16x32_bf16(       \
                af[m_][1], BF[n_][1], acc[(MB)+m_][(NB)+n_], 0, 0, 0);             \
        }                                                                          \
} while (0)

#define BAR   __builtin_amdgcn_s_barrier()
#define LGKM0 asm volatile("s_waitcnt lgkmcnt(0)")
#define LGKM8 asm volatile("s_waitcnt lgkmcnt(8)")
#define VM4   asm volatile("s_waitcnt vmcnt(4)" ::: "memory")
#define PRIO1 __builtin_amdgcn_s_setprio(1)
#define PRIO0 __builtin_amdgcn_s_setprio(0)

    f32x4 acc[8][4];
    #pragma unroll
    for (int i = 0; i < 8; ++i)
        #pragma unroll
        for (int j = 0; j < 4; ++j)
            acc[i][j] = (f32x4){0.f, 0.f, 0.f, 0.f};

    bf16x8 af[4][2], bfA[2][2], bfB[2][2];

    // prologue: t0 full (8 loads) + t1-B (4 loads); vmcnt(4) retires t0.
    STAGE_B(0, 0, 0);  STAGE_B(0, 1, 0);
    STAGE_A(0, 0, 0);  STAGE_A(0, 1, 0);
    STAGE_B(1, 0, 1);  STAGE_B(1, 1, 1);
    VM4;  BAR;

    #pragma unroll 1
    for (int it = 0; it < NIT; ++it) {
        const int ta = 2 * it + 1;                            // <=15 always
        const int tb = (2 * it + 2 <= 15) ? 2 * it + 2 : 15;
        const int tc = (2 * it + 3 <= 15) ? 2 * it + 3 : 15;

        // ---- K-tile 2it (buf 0) ----
        // j=0
        RD_A(0, 0);  RD_B(0, 0, bfA);
        STAGE_A(1, 0, ta);
        LGKM8;  BAR;  LGKM0;
        PRIO1;  MM(0, 0, bfA);  PRIO0;  BAR;
        // j=1
        RD_B(0, 2, bfB);
        STAGE_A(1, 1, ta);
        BAR;  LGKM0;
        PRIO1;  MM(0, 2, bfB);  PRIO0;  BAR;
        // j=2  (buf0-B free after j1)
        RD_A(0, 4);
        STAGE_B(0, 0, tb);
        BAR;  LGKM0;
        PRIO1;  MM(4, 0, bfA);  PRIO0;  BAR;
        // j=3
        STAGE_B(0, 1, tb);
        BAR;
        PRIO1;  MM(4, 2, bfB);  PRIO0;
        VM4;  BAR;               // retires t_{2it+1} (B@prev j6/j7, A@j0/j1)

        // ---- K-tile 2it+1 (buf 1) ----
        // j=4  (buf0-A free after j2)
        RD_A(1, 0);  RD_B(1, 0, bfA);
        STAGE_A(0, 0, tb);
        LGKM8;  BAR;  LGKM0;
        PRIO1;  MM(0, 0, bfA);  PRIO0;  BAR;
        // j=5
        RD_B(1, 2, bfB);
        STAGE_A(0, 1, tb);
        BAR;  LGKM0;
        PRIO1;  MM(0, 2, bfB);  PRIO0;  BAR;
        // j=6  (buf1-B free after j5)
        RD_A(1, 4);
        STAGE_B(1, 0, tc);
        BAR;  LGKM0;
        PRIO1;  MM(4, 0, bfA);  PRIO0;  BAR;
        // j=7
        STAGE_B(1, 1, tc);
        BAR;
        PRIO1;  MM(4, 2, bfB);  PRIO0;
        VM4;  BAR;               // retires t_{2it+2} (B@j2/j3, A@j4/j5)
    }

    asm volatile("s_waitcnt vmcnt(0)" ::: "memory");   // drain tail dups

    // epilogue: C/D layout col = lane&15, row = (lane>>4)*4 + r
    const int crow = (lane >> 4) * 4;
    const int ccol = lane & 15;
    float bv4[4];
    #pragma unroll
    for (int ni = 0; ni < 4; ++ni)
        bv4[ni] = bias[n0 + wc * 64 + ni * 16 + ccol];
    #pragma unroll
    for (int mi = 0; mi < 8; ++mi) {
        #pragma unroll
        for (int r = 0; r < 4; ++r) {
            const size_t rowg = (size_t)(m0 + wr * 128 + mi * 16 + crow + r) * N;
            #pragma unroll
            for (int ni = 0; ni < 4; ++ni) {
                const int col = n0 + wc * 64 + ni * 16 + ccol;
                float v = acc[mi][ni][r] + bv4[ni];
                if constexpr (std::is_same<OutT, float>::value) {
                    C[rowg + col] = v;
                } else {
                    C[rowg + col] = f2b(v);
                }
            }
        }
    }
#undef GLD
#undef STAGE_A
#undef STAGE_B
#undef RD_A
#undef RD_B
#undef MM
#undef BAR
#undef LGKM0
#undef LGKM8
#undef VM4
#undef PRIO1
#undef PRIO0
}

// ---------------- per-token head-mixing attention ----------------------
__global__ __launch_bounds__(256) void k_attn(
    const short* __restrict__ QKV, short* __restrict__ O)
{
    __shared__ short Ks[16][1032];
    __shared__ short Vs[16][1032];

    const int tid = threadIdx.x;
    const int tok0 = blockIdx.x * 16;

    for (int i = tid; i < 2048; i += 256) {
        int t = i >> 7;
        int j = i & 127;
        const size_t base = (size_t)(tok0 + t) * QKV_STRIDE;
        *reinterpret_cast<short8_t*>(&Ks[t][j * 8]) =
            *reinterpret_cast<const short8_t*>(&QKV[base + 1024 + j * 8]);
        *reinterpret_cast<short8_t*>(&Vs[t][j * 8]) =
            *reinterpret_cast<const short8_t*>(&QKV[base + 2048 + j * 8]);
    }
    __syncthreads();

    const int tl = tid >> 4;
    const int h  = tid & 15;

    float qf[64];
    const short* qp = QKV + (size_t)(tok0 + tl) * QKV_STRIDE + h * HD;
    #pragma unroll
    for (int i = 0; i < 8; ++i) {
        short8_t v = *reinterpret_cast<const short8_t*>(&qp[i * 8]);
        #pragma unroll
        for (int j = 0; j < 8; ++j) qf[i * 8 + j] = b2f(v[j]);
    }

    float s[16];
    #pragma unroll
    for (int g = 0; g < 16; ++g) {
        float a = 0.f;
        #pragma unroll
        for (int i = 0; i < 8; ++i) {
            short8_t kv = *reinterpret_cast<const short8_t*>(&Ks[tl][g * HD + i * 8]);
            #pragma unroll
            for (int j = 0; j < 8; ++j) a += qf[i * 8 + j] * b2f(kv[j]);
        }
        s[g] = a * 0.125f;
    }
    float mx = s[0];
    #pragma unroll
    for (int g = 1; g < 16; ++g) mx = fmaxf(mx, s[g]);
    float l = 0.f;
    #pragma unroll
    for (int g = 0; g < 16; ++g) { s[g] = __expf(s[g] - mx); l += s[g]; }
    const float inv = 1.f / l;
    #pragma unroll
    for (int g = 0; g < 16; ++g) s[g] *= inv;

    short* op = O + (size_t)(tok0 + tl) * E_DIM + h * HD;
    #pragma unroll
    for (int c = 0; c < 4; ++c) {
        float a[16];
        #pragma unroll
        for (int j = 0; j < 16; ++j) a[j] = 0.f;
        #pragma unroll
        for (int g = 0; g < 16; ++g) {
            short8_t v0 = *reinterpret_cast<const short8_t*>(&Vs[tl][g * HD + c * 16]);
            short8_t v1 = *reinterpret_cast<const short8_t*>(&Vs[tl][g * HD + c * 16 + 8]);
            #pragma unroll
            for (int j = 0; j < 8; ++j) {
                a[j]     += s[g] * b2f(v0[j]);
                a[8 + j] += s[g] * b2f(v1[j]);
            }
        }
        short8_t o0, o1;
        #pragma unroll
        for (int j = 0; j < 8; ++j) { o0[j] = f2b(a[j]); o1[j] = f2b(a[8 + j]); }
        *reinterpret_cast<short8_t*>(&op[c * 16])     = o0;
        *reinterpret_cast<short8_t*>(&op[c * 16 + 8]) = o1;
    }
}

extern "C" void kernel_launch(void* const* d_in, const int* in_sizes, int n_in,
                              void* d_out, int out_size, void* d_ws, size_t ws_size,
                              hipStream_t stream) {
    const float* x  = (const float*)d_in[0];
    const float* Wq = (const float*)d_in[1];
    const float* bq = (const float*)d_in[2];
    const float* Wk = (const float*)d_in[3];
    const float* bk = (const float*)d_in[4];
    const float* Wv = (const float*)d_in[5];
    const float* bv = (const float*)d_in[6];
    const float* Wo = (const float*)d_in[7];
    const float* bo = (const float*)d_in[8];
    float* out = (float*)d_out;

    const int T = in_sizes[0] / E_DIM;      // 32768 tokens
    char* ws = (char*)d_ws;
    const size_t SZ_X    = (size_t)T * E_DIM * 2;
    const size_t SZ_WQKV = (size_t)3 * E_DIM * E_DIM * 2;
    const size_t SZ_W    = (size_t)E_DIM * E_DIM * 2;
    const size_t SZ_B    = 3072 * sizeof(float) + 4096;

    short* xb    = (short*)(ws);
    short* Wqkvb = (short*)(ws + SZ_X);
    short* Wob   = (short*)(ws + SZ_X + SZ_WQKV);
    float* bqkv  = (float*)(ws + SZ_X + SZ_WQKV + SZ_W);
    short* QKVb  = (short*)(ws + SZ_X + SZ_WQKV + SZ_W + SZ_B);
    short* Ab    = xb;   // reuse x-bf16 buffer for attention output

    const int n4x = T * E_DIM / 4;          // 8M float4
    const int n4w = E_DIM * E_DIM / 4;      // 256K float4
    const int nprep = n4x + 4 * n4w + 768;
    k_prep<<<dim3((nprep + 255) / 256), dim3(256), 0, stream>>>(
        x, Wq, Wk, Wv, Wo, bq, bk, bv, xb, Wqkvb, Wob, bqkv, n4x, n4w);

    // fused QKV GEMM: [T][3072]
    k_gemm256<short><<<dim3((T / 256) * (QKV_STRIDE / 256)), dim3(512), 0, stream>>>(
        xb, Wqkvb, bqkv, QKVb, QKV_STRIDE / 256, QKV_STRIDE);

    k_attn<<<dim3(T / 16), dim3(256), 0, stream>>>(QKVb, Ab);

    // output GEMM: [T][1024] fp32
    k_gemm256<float><<<dim3((T / 256) * (E_DIM / 256)), dim3(512), 0, stream>>>(
        Ab, Wob, bo, out, E_DIM / 256, E_DIM);
}

// Round 12
// 389.441 us; speedup vs baseline: 1.1738x; 1.0091x over previous
//
#include <hip/hip_runtime.h>
#include <hip/hip_bf16.h>
#include <cstdint>
#include <type_traits>

#define GLOBAL_AS __attribute__((address_space(1)))
#define LDS_AS    __attribute__((address_space(3)))

typedef short bf16x8 __attribute__((ext_vector_type(8)));
typedef short short8_t __attribute__((ext_vector_type(8)));
typedef float f32x4  __attribute__((ext_vector_type(4)));

static constexpr int E_DIM = 1024;
static constexpr int HD = 64;
static constexpr int QKV_STRIDE = 3072;
static constexpr int KDIM = 1024;        // K for both GEMMs
static constexpr int NTK  = KDIM / 64;   // 16 K-tiles
static constexpr int NIT  = NTK / 2;     // 8 iterations (2 K-tiles each)

__device__ __forceinline__ float b2f(short s) {
    union { unsigned u; float f; } x;
    x.u = ((unsigned)(unsigned short)s) << 16;
    return x.f;
}
__device__ __forceinline__ short f2b(float f) {
    union { float f; unsigned u; } x; x.f = f;
    unsigned r = x.u + 0x7FFF + ((x.u >> 16) & 1);
    return (short)(r >> 16);
}

// ---- fused prep: x->bf16, Wq/Wk/Wv->Wqkvb, Wo->Wob, bias concat ----
__global__ __launch_bounds__(256) void k_prep(
    const float* __restrict__ x,
    const float* __restrict__ Wq, const float* __restrict__ Wk,
    const float* __restrict__ Wv, const float* __restrict__ Wo,
    const float* __restrict__ bq, const float* __restrict__ bk,
    const float* __restrict__ bv,
    short* __restrict__ xb, short* __restrict__ Wqkvb, short* __restrict__ Wob,
    float* __restrict__ bqkv, int n4x, int n4w)
{
    int i = blockIdx.x * 256 + threadIdx.x;
    const float* src;
    short* dst;
    int j;
    if (i < n4x)                       { src = x;  dst = xb;                  j = i; }
    else if (i < n4x + n4w)            { src = Wq; dst = Wqkvb;               j = i - n4x; }
    else if (i < n4x + 2 * n4w)        { src = Wk; dst = Wqkvb + 4 * n4w;     j = i - n4x - n4w; }
    else if (i < n4x + 3 * n4w)        { src = Wv; dst = Wqkvb + 8 * n4w;     j = i - n4x - 2 * n4w; }
    else if (i < n4x + 4 * n4w)        { src = Wo; dst = Wob;                 j = i - n4x - 3 * n4w; }
    else {
        int b = i - (n4x + 4 * n4w);
        if (b < 768) {
            #pragma unroll
            for (int e = 0; e < 4; ++e) {
                int idx = b * 4 + e;
                float v = (idx < 1024) ? bq[idx] : (idx < 2048 ? bk[idx - 1024] : bv[idx - 2048]);
                bqkv[idx] = v;
            }
        }
        return;
    }
    float4 v = reinterpret_cast<const float4*>(src)[j];
    short4 o;
    o.x = f2b(v.x); o.y = f2b(v.y); o.z = f2b(v.z); o.w = f2b(v.w);
    reinterpret_cast<short4*>(dst)[j] = o;
}

// ==== 256x256 bf16 GEMM — MFMA-first single-barrier phases ====
// Phase p: { BAR; MFMA on frags read at tail of p-1; issue reads for p+1;
// issue stage }. Reads are PRE-barrier relative to their consuming MFMA ->
// LDS drain overlaps other waves' MFMA (the two-barrier skeleton serialized
// them; measured phase ~= LDS + MFMA sum across R4-R11).
// Frag liveness: each read target is dead once this phase's MFMA has issued
// (program order MFMA->reads) -> SAME register sets as before (af, bfA, bfB).
// Ring (per iter, consume E=2it buf0 / O=2it+1 buf1; E2=2it+2, O2=2it+3):
//   reads: p0:bB(E) p1:af1(E) p3:af0(O)+bA(O) p4:bB(O) p5:af1(O)
//          p7:af0(E')+bA(E')   (p2,p6: none)
//   stages: p0:A1(O) p1:B0(E2) p2:B1(E2) p3:A0(E2) p4:A1(E2)
//           p5:B0(O2) p6:B1(O2) p7:A0(O2)
//   vmcnt(4) at p2/p6 tails: FIFO 12->4, retires the tile consumed after the
//   next barrier (O before p3-reads; E2 before p7-reads); all staged >=2
//   phases before their first read; overwrites >=1 barrier after last read.
// Prologue: t0 full + t1{B0,B1,A0} = 14 loads; vmcnt(6) retires t0; BAR;
// read af0(t0)+bA(t0). Tail: clamped stages land in dead regions (benign);
// iter7's p7 reads are dead (never consumed).
template <typename OutT>
__global__ __launch_bounds__(512, 2) void k_gemm256(
    const short* __restrict__ A,    // [M][KDIM]
    const short* __restrict__ Bm,   // [N][KDIM]
    const float* __restrict__ bias, // [N]
    OutT* __restrict__ C,           // [M][N]
    int NT_N, int N)
{
    __shared__ short lds[65536];   // [buf]*32768 + [mat]*16384 + [half]*8192

    const int tid  = threadIdx.x;
    const int lane = tid & 63;
    const int wv   = tid >> 6;
    const int wr   = wv >> 2;       // 0..1 M half
    const int wc   = wv & 3;        // 0..3 N quarter
    const int frow = lane & 15;
    const int ks   = lane >> 4;     // k-slot within 32-k
    const int sw   = frow & 7;      // read-side swizzle key
    const int sl0  = ((0 + ks) ^ sw) * 8;   // kk=0 slot offset (shorts)
    const int sl1  = ((4 + ks) ^ sw) * 8;   // kk=1

    // bijective XCD swizzle (grid%8==0), n-fastest (neighbors share A-panel)
    const int nwg = gridDim.x, nper = nwg >> 3, bid = blockIdx.x;
    const int swz = (bid & 7) * nper + (bid >> 3);
    const int m0  = (swz / NT_N) * 256;
    const int n0  = (swz % NT_N) * 256;

    // read bases (shorts, within buf)
    const int ArdBase = wr * 8192;
    const int BrdBase = 16384 + (wc >> 1) * 8192 + (wc & 1) * 4096;

    // staging: thread covers rows srow and srow+64 of a 128-row half
    const int srow = tid >> 3;                       // 0..63
    const int ssl  = ((tid & 7) ^ (srow & 7)) * 8;   // pre-swizzled source slot
    const int sdst = tid * 8;                        // linear LDS dest

#define GLD(SRC, DST) __builtin_amdgcn_global_load_lds(                            \
        (const GLOBAL_AS short*)(SRC), (LDS_AS short*)(DST), 16, 0, 0)
#define STAGE_A(BUF, HALF, T) do {                                                 \
    const short* s_ = A + (size_t)(m0 + (HALF) * 128 + srow) * KDIM + (T) * 64 + ssl; \
    short* d_ = &lds[(BUF) * 32768 + (HALF) * 8192 + sdst];                        \
    GLD(s_, d_);  GLD(s_ + (size_t)64 * KDIM, d_ + 4096);                          \
} while (0)
#define STAGE_B(BUF, HALF, T) do {                                                 \
    const short* s_ = Bm + (size_t)(n0 + (HALF) * 128 + srow) * KDIM + (T) * 64 + ssl; \
    short* d_ = &lds[(BUF) * 32768 + 16384 + (HALF) * 8192 + sdst];                \
    GLD(s_, d_);  GLD(s_ + (size_t)64 * KDIM, d_ + 4096);                          \
} while (0)

#define RD_A(BUF, MIB) do {                                                        \
    _Pragma("unroll")                                                              \
    for (int m_ = 0; m_ < 4; ++m_) {                                               \
        const short* p_ = &lds[(BUF) * 32768 + ArdBase + ((MIB) + m_) * 1024 + frow * 64]; \
        af[m_][0] = *(const bf16x8*)(p_ + sl0);                                    \
        af[m_][1] = *(const bf16x8*)(p_ + sl1);                                    \
    }                                                                              \
} while (0)
#define RD_B(BUF, NIB, BF) do {                                                    \
    _Pragma("unroll")                                                              \
    for (int n_ = 0; n_ < 2; ++n_) {                                               \
        const short* p_ = &lds[(BUF) * 32768 + BrdBase + ((NIB) + n_) * 1024 + frow * 64]; \
        BF[n_][0] = *(const bf16x8*)(p_ + sl0);                                    \
        BF[n_][1] = *(const bf16x8*)(p_ + sl1);                                    \
    }                                                                              \
} while (0)

#define MM(MB, NB, BF) do {                                                        \
    __builtin_amdgcn_s_setprio(1);                                                 \
    _Pragma("unroll")                                                              \
    for (int m_ = 0; m_ < 4; ++m_)                                                 \
        _Pragma("unroll")                                                          \
        for (int n_ = 0; n_ < 2; ++n_) {                                           \
            acc[(MB)+m_][(NB)+n_] = __builtin_amdgcn_mfma_f32_16x16x32_bf16(       \
                af[m_][0], BF[n_][0], acc[(MB)+m_][(NB)+n_], 0, 0, 0);             \
            acc[(MB)+m_][(NB)+n_] = __builtin_amdgcn_mfma_f32_16x16x32_bf16(       \
                af[m_][1], BF[n_][1], acc[(MB)+m_][(NB)+n_], 0, 0, 0);             \
        }                                                                          \
    __builtin_amdgcn_s_setprio(0);                                                 \
} while (0)

#define BAR   __builtin_amdgcn_s_barrier()
#define VM4   asm volatile("s_waitcnt vmcnt(4)" ::: "memory")
#define VM6   asm volatile("s_waitcnt vmcnt(6)" ::: "memory")

    f32x4 acc[8][4];
    #pragma unroll
    for (int i = 0; i < 8; ++i)
        #pragma unroll
        for (int j = 0; j < 4; ++j)
            acc[i][j] = (f32x4){0.f, 0.f, 0.f, 0.f};

    bf16x8 af[4][2], bfA[2][2], bfB[2][2];

    // prologue: t0 full (8) + t1 {B0,B1,A0} (6); VM6 retires t0; BAR; Q0 reads.
    STAGE_B(0, 0, 0);  STAGE_B(0, 1, 0);
    STAGE_A(0, 0, 0);  STAGE_A(0, 1, 0);
    STAGE_B(1, 0, 1);  STAGE_B(1, 1, 1);
    STAGE_A(1, 0, 1);
    VM6;  BAR;
    RD_A(0, 0);  RD_B(0, 0, bfA);        // af0(t0), bA(t0) — pre-BAR(p0)

    #pragma unroll 1
    for (int it = 0; it < NIT; ++it) {
        const int ta = 2 * it + 1;                            // <=15 always
        const int tb = (2 * it + 2 <= 15) ? 2 * it + 2 : 15;  // E2 (buf0)
        const int tc = (2 * it + 3 <= 15) ? 2 * it + 3 : 15;  // O2 (buf1)

        // p0: Q0(E)
        BAR;
        MM(0, 0, bfA);
        RD_B(0, 2, bfB);                 // bB(E)
        STAGE_A(1, 1, ta);               // A1(O)
        // p1: Q1(E)
        BAR;
        MM(0, 2, bfB);
        RD_A(0, 4);                      // af1(E)
        STAGE_B(0, 0, tb);               // B0(E2)
        // p2: Q2(E)
        BAR;
        MM(4, 0, bfA);
        STAGE_B(0, 1, tb);               // B1(E2)
        VM4;                             // O fully resident before p3-reads
        // p3: Q3(E)
        BAR;
        MM(4, 2, bfB);
        RD_A(1, 0);  RD_B(1, 0, bfA);    // af0(O), bA(O)
        STAGE_A(0, 0, tb);               // A0(E2)
        // p4: Q0(O)
        BAR;
        MM(0, 0, bfA);
        RD_B(1, 2, bfB);                 // bB(O)
        STAGE_A(0, 1, tb);               // A1(E2)
        // p5: Q1(O)
        BAR;
        MM(0, 2, bfB);
        RD_A(1, 4);                      // af1(O)
        STAGE_B(1, 0, tc);               // B0(O2)
        // p6: Q2(O)
        BAR;
        MM(4, 0, bfA);
        STAGE_B(1, 1, tc);               // B1(O2)
        VM4;                             // E2 fully resident before p7-reads
        // p7: Q3(O)
        BAR;
        MM(4, 2, bfB);
        RD_A(0, 0);  RD_B(0, 0, bfA);    // af0(E'), bA(E') — next iter's Q0
        STAGE_A(1, 0, tc);               // A0(O2)
    }

    asm volatile("s_waitcnt vmcnt(0)" ::: "memory");   // drain tail dups

    // epilogue: C/D layout col = lane&15, row = (lane>>4)*4 + r
    const int crow = (lane >> 4) * 4;
    const int ccol = lane & 15;
    float bv4[4];
    #pragma unroll
    for (int ni = 0; ni < 4; ++ni)
        bv4[ni] = bias[n0 + wc * 64 + ni * 16 + ccol];
    #pragma unroll
    for (int mi = 0; mi < 8; ++mi) {
        #pragma unroll
        for (int r = 0; r < 4; ++r) {
            const size_t rowg = (size_t)(m0 + wr * 128 + mi * 16 + crow + r) * N;
            #pragma unroll
            for (int ni = 0; ni < 4; ++ni) {
                const int col = n0 + wc * 64 + ni * 16 + ccol;
                float v = acc[mi][ni][r] + bv4[ni];
                if constexpr (std::is_same<OutT, float>::value) {
                    C[rowg + col] = v;
                } else {
                    C[rowg + col] = f2b(v);
                }
            }
        }
    }
#undef GLD
#undef STAGE_A
#undef STAGE_B
#undef RD_A
#undef RD_B
#undef MM
#undef BAR
#undef VM4
#undef VM6
}

// ---------------- per-token head-mixing attention ----------------------
__global__ __launch_bounds__(256) void k_attn(
    const short* __restrict__ QKV, short* __restrict__ O)
{
    __shared__ short Ks[16][1032];
    __shared__ short Vs[16][1032];

    const int tid = threadIdx.x;
    const int tok0 = blockIdx.x * 16;

    for (int i = tid; i < 2048; i += 256) {
        int t = i >> 7;
        int j = i & 127;
        const size_t base = (size_t)(tok0 + t) * QKV_STRIDE;
        *reinterpret_cast<short8_t*>(&Ks[t][j * 8]) =
            *reinterpret_cast<const short8_t*>(&QKV[base + 1024 + j * 8]);
        *reinterpret_cast<short8_t*>(&Vs[t][j * 8]) =
            *reinterpret_cast<const short8_t*>(&QKV[base + 2048 + j * 8]);
    }
    __syncthreads();

    const int tl = tid >> 4;
    const int h  = tid & 15;

    float qf[64];
    const short* qp = QKV + (size_t)(tok0 + tl) * QKV_STRIDE + h * HD;
    #pragma unroll
    for (int i = 0; i < 8; ++i) {
        short8_t v = *reinterpret_cast<const short8_t*>(&qp[i * 8]);
        #pragma unroll
        for (int j = 0; j < 8; ++j) qf[i * 8 + j] = b2f(v[j]);
    }

    float s[16];
    #pragma unroll
    for (int g = 0; g < 16; ++g) {
        float a = 0.f;
        #pragma unroll
        for (int i = 0; i < 8; ++i) {
            short8_t kv = *reinterpret_cast<const short8_t*>(&Ks[tl][g * HD + i * 8]);
            #pragma unroll
            for (int j = 0; j < 8; ++j) a += qf[i * 8 + j] * b2f(kv[j]);
        }
        s[g] = a * 0.125f;
    }
    float mx = s[0];
    #pragma unroll
    for (int g = 1; g < 16; ++g) mx = fmaxf(mx, s[g]);
    float l = 0.f;
    #pragma unroll
    for (int g = 0; g < 16; ++g) { s[g] = __expf(s[g] - mx); l += s[g]; }
    const float inv = 1.f / l;
    #pragma unroll
    for (int g = 0; g < 16; ++g) s[g] *= inv;

    short* op = O + (size_t)(tok0 + tl) * E_DIM + h * HD;
    #pragma unroll
    for (int c = 0; c < 4; ++c) {
        float a[16];
        #pragma unroll
        for (int j = 0; j < 16; ++j) a[j] = 0.f;
        #pragma unroll
        for (int g = 0; g < 16; ++g) {
            short8_t v0 = *reinterpret_cast<const short8_t*>(&Vs[tl][g * HD + c * 16]);
            short8_t v1 = *reinterpret_cast<const short8_t*>(&Vs[tl][g * HD + c * 16 + 8]);
            #pragma unroll
            for (int j = 0; j < 8; ++j) {
                a[j]     += s[g] * b2f(v0[j]);
                a[8 + j] += s[g] * b2f(v1[j]);
            }
        }
        short8_t o0, o1;
        #pragma unroll
        for (int j = 0; j < 8; ++j) { o0[j] = f2b(a[j]); o1[j] = f2b(a[8 + j]); }
        *reinterpret_cast<short8_t*>(&op[c * 16])     = o0;
        *reinterpret_cast<short8_t*>(&op[c * 16 + 8]) = o1;
    }
}

extern "C" void kernel_launch(void* const* d_in, const int* in_sizes, int n_in,
                              void* d_out, int out_size, void* d_ws, size_t ws_size,
                              hipStream_t stream) {
    const float* x  = (const float*)d_in[0];
    const float* Wq = (const float*)d_in[1];
    const float* bq = (const float*)d_in[2];
    const float* Wk = (const float*)d_in[3];
    const float* bk = (const float*)d_in[4];
    const float* Wv = (const float*)d_in[5];
    const float* bv = (const float*)d_in[6];
    const float* Wo = (const float*)d_in[7];
    const float* bo = (const float*)d_in[8];
    float* out = (float*)d_out;

    const int T = in_sizes[0] / E_DIM;      // 32768 tokens
    char* ws = (char*)d_ws;
    const size_t SZ_X    = (size_t)T * E_DIM * 2;
    const size_t SZ_WQKV = (size_t)3 * E_DIM * E_DIM * 2;
    const size_t SZ_W    = (size_t)E_DIM * E_DIM * 2;
    const size_t SZ_B    = 3072 * sizeof(float) + 4096;

    short* xb    = (short*)(ws);
    short* Wqkvb = (short*)(ws + SZ_X);
    short* Wob   = (short*)(ws + SZ_X + SZ_WQKV);
    float* bqkv  = (float*)(ws + SZ_X + SZ_WQKV + SZ_W);
    short* QKVb  = (short*)(ws + SZ_X + SZ_WQKV + SZ_W + SZ_B);
    short* Ab    = xb;   // reuse x-bf16 buffer for attention output

    const int n4x = T * E_DIM / 4;          // 8M float4
    const int n4w = E_DIM * E_DIM / 4;      // 256K float4
    const int nprep = n4x + 4 * n4w + 768;
    k_prep<<<dim3((nprep + 255) / 256), dim3(256), 0, stream>>>(
        x, Wq, Wk, Wv, Wo, bq, bk, bv, xb, Wqkvb, Wob, bqkv, n4x, n4w);

    // fused QKV GEMM: [T][3072]
    k_gemm256<short><<<dim3((T / 256) * (QKV_STRIDE / 256)), dim3(512), 0, stream>>>(
        xb, Wqkvb, bqkv, QKVb, QKV_STRIDE / 256, QKV_STRIDE);

    k_attn<<<dim3(T / 16), dim3(256), 0, stream>>>(QKVb, Ab);

    // output GEMM: [T][1024] fp32
    k_gemm256<float><<<dim3((T / 256) * (E_DIM / 256)), dim3(512), 0, stream>>>(
        Ab, Wob, bo, out, E_DIM / 256, E_DIM);
}

// Round 13
// 389.382 us; speedup vs baseline: 1.1740x; 1.0002x over previous
//
#include <hip/hip_runtime.h>
#include <hip/hip_bf16.h>
#include <cstdint>
#include <type_traits>

#define GLOBAL_AS __attribute__((address_space(1)))
#define LDS_AS    __attribute__((address_space(3)))

typedef short bf16x8 __attribute__((ext_vector_type(8)));
typedef short short8_t __attribute__((ext_vector_type(8)));
typedef float f32x4  __attribute__((ext_vector_type(4)));

static constexpr int E_DIM = 1024;
static constexpr int HD = 64;
static constexpr int QKV_STRIDE = 3072;
static constexpr int KDIM = 1024;        // K for both GEMMs
static constexpr int NTK  = KDIM / 64;   // 16 K-tiles
static constexpr int NIT  = NTK / 2;     // 8 iterations (2 K-tiles each)

__device__ __forceinline__ float b2f(short s) {
    union { unsigned u; float f; } x;
    x.u = ((unsigned)(unsigned short)s) << 16;
    return x.f;
}
__device__ __forceinline__ short f2b(float f) {
    union { float f; unsigned u; } x; x.f = f;
    unsigned r = x.u + 0x7FFF + ((x.u >> 16) & 1);
    return (short)(r >> 16);
}

// ---- fused prep: x->bf16, Wq/Wk/Wv->Wqkvb, Wo->Wob, bias concat ----
__global__ __launch_bounds__(256) void k_prep(
    const float* __restrict__ x,
    const float* __restrict__ Wq, const float* __restrict__ Wk,
    const float* __restrict__ Wv, const float* __restrict__ Wo,
    const float* __restrict__ bq, const float* __restrict__ bk,
    const float* __restrict__ bv,
    short* __restrict__ xb, short* __restrict__ Wqkvb, short* __restrict__ Wob,
    float* __restrict__ bqkv, int n4x, int n4w)
{
    int i = blockIdx.x * 256 + threadIdx.x;
    const float* src;
    short* dst;
    int j;
    if (i < n4x)                       { src = x;  dst = xb;                  j = i; }
    else if (i < n4x + n4w)            { src = Wq; dst = Wqkvb;               j = i - n4x; }
    else if (i < n4x + 2 * n4w)        { src = Wk; dst = Wqkvb + 4 * n4w;     j = i - n4x - n4w; }
    else if (i < n4x + 3 * n4w)        { src = Wv; dst = Wqkvb + 8 * n4w;     j = i - n4x - 2 * n4w; }
    else if (i < n4x + 4 * n4w)        { src = Wo; dst = Wob;                 j = i - n4x - 3 * n4w; }
    else {
        int b = i - (n4x + 4 * n4w);
        if (b < 768) {
            #pragma unroll
            for (int e = 0; e < 4; ++e) {
                int idx = b * 4 + e;
                float v = (idx < 1024) ? bq[idx] : (idx < 2048 ? bk[idx - 1024] : bv[idx - 2048]);
                bqkv[idx] = v;
            }
        }
        return;
    }
    float4 v = reinterpret_cast<const float4*>(src)[j];
    short4 o;
    o.x = f2b(v.x); o.y = f2b(v.y); o.z = f2b(v.z); o.w = f2b(v.w);
    reinterpret_cast<short4*>(dst)[j] = o;
}

// ==== 256x256 bf16 GEMM — MFMA-first phases, balanced reads, 2-phase bfA ====
// R12 skeleton (single barrier/phase, MFMA on prev-read frags, then reads,
// then stage). Deltas:
//  * balanced reads 4/8 per phase; bfA read at p2/p6 (2-phase lead);
//    bfB read BEFORE MM at p0/p4 (that MM doesn't consume bfB).
//  * vmcnt: VM6 at p1/p5 tails (secures B-pair of next tile before its
//    bfA read at p2/p6), VM4 at p2/p6 tails (secures A-pair before p3/p7
//    reads). FIFO verified: steady state enters each iter with 6 loads
//    outstanding; each wait retires exactly the half-tile pair read after
//    the following barrier.
// Read legality (regs): af read after the phase's FULL MM (af live in every
// MM); bfA read after its last consuming MM (p2/p6); bfB after p3/p7 via
// placement at p4/p0 pre-MM. Overwrites: every STAGE target's last read
// drains >=1 barrier before the write (same as R9-R12, unchanged schedule).
template <typename OutT>
__global__ __launch_bounds__(512, 2) void k_gemm256(
    const short* __restrict__ A,    // [M][KDIM]
    const short* __restrict__ Bm,   // [N][KDIM]
    const float* __restrict__ bias, // [N]
    OutT* __restrict__ C,           // [M][N]
    int NT_N, int N)
{
    __shared__ short lds[65536];   // [buf]*32768 + [mat]*16384 + [half]*8192

    const int tid  = threadIdx.x;
    const int lane = tid & 63;
    const int wv   = tid >> 6;
    const int wr   = wv >> 2;       // 0..1 M half
    const int wc   = wv & 3;        // 0..3 N quarter
    const int frow = lane & 15;
    const int ks   = lane >> 4;     // k-slot within 32-k
    const int sw   = frow & 7;      // read-side swizzle key
    const int sl0  = ((0 + ks) ^ sw) * 8;   // kk=0 slot offset (shorts)
    const int sl1  = ((4 + ks) ^ sw) * 8;   // kk=1

    // bijective XCD swizzle (grid%8==0), n-fastest (neighbors share A-panel)
    const int nwg = gridDim.x, nper = nwg >> 3, bid = blockIdx.x;
    const int swz = (bid & 7) * nper + (bid >> 3);
    const int m0  = (swz / NT_N) * 256;
    const int n0  = (swz % NT_N) * 256;

    // read bases (shorts, within buf)
    const int ArdBase = wr * 8192;
    const int BrdBase = 16384 + (wc >> 1) * 8192 + (wc & 1) * 4096;

    // staging: thread covers rows srow and srow+64 of a 128-row half
    const int srow = tid >> 3;                       // 0..63
    const int ssl  = ((tid & 7) ^ (srow & 7)) * 8;   // pre-swizzled source slot
    const int sdst = tid * 8;                        // linear LDS dest

#define GLD(SRC, DST) __builtin_amdgcn_global_load_lds(                            \
        (const GLOBAL_AS short*)(SRC), (LDS_AS short*)(DST), 16, 0, 0)
#define STAGE_A(BUF, HALF, T) do {                                                 \
    const short* s_ = A + (size_t)(m0 + (HALF) * 128 + srow) * KDIM + (T) * 64 + ssl; \
    short* d_ = &lds[(BUF) * 32768 + (HALF) * 8192 + sdst];                        \
    GLD(s_, d_);  GLD(s_ + (size_t)64 * KDIM, d_ + 4096);                          \
} while (0)
#define STAGE_B(BUF, HALF, T) do {                                                 \
    const short* s_ = Bm + (size_t)(n0 + (HALF) * 128 + srow) * KDIM + (T) * 64 + ssl; \
    short* d_ = &lds[(BUF) * 32768 + 16384 + (HALF) * 8192 + sdst];                \
    GLD(s_, d_);  GLD(s_ + (size_t)64 * KDIM, d_ + 4096);                          \
} while (0)

#define RD_A(BUF, MIB) do {                                                        \
    _Pragma("unroll")                                                              \
    for (int m_ = 0; m_ < 4; ++m_) {                                               \
        const short* p_ = &lds[(BUF) * 32768 + ArdBase + ((MIB) + m_) * 1024 + frow * 64]; \
        af[m_][0] = *(const bf16x8*)(p_ + sl0);                                    \
        af[m_][1] = *(const bf16x8*)(p_ + sl1);                                    \
    }                                                                              \
} while (0)
#define RD_B(BUF, NIB, BF) do {                                                    \
    _Pragma("unroll")                                                              \
    for (int n_ = 0; n_ < 2; ++n_) {                                               \
        const short* p_ = &lds[(BUF) * 32768 + BrdBase + ((NIB) + n_) * 1024 + frow * 64]; \
        BF[n_][0] = *(const bf16x8*)(p_ + sl0);                                    \
        BF[n_][1] = *(const bf16x8*)(p_ + sl1);                                    \
    }                                                                              \
} while (0)

#define MM(MB, NB, BF) do {                                                        \
    __builtin_amdgcn_s_setprio(1);                                                 \
    _Pragma("unroll")                                                              \
    for (int m_ = 0; m_ < 4; ++m_)                                                 \
        _Pragma("unroll")                                                          \
        for (int n_ = 0; n_ < 2; ++n_) {                                           \
            acc[(MB)+m_][(NB)+n_] = __builtin_amdgcn_mfma_f32_16x16x32_bf16(       \
                af[m_][0], BF[n_][0], acc[(MB)+m_][(NB)+n_], 0, 0, 0);             \
            acc[(MB)+m_][(NB)+n_] = __builtin_amdgcn_mfma_f32_16x16x32_bf16(       \
                af[m_][1], BF[n_][1], acc[(MB)+m_][(NB)+n_], 0, 0, 0);             \
        }                                                                          \
    __builtin_amdgcn_s_setprio(0);                                                 \
} while (0)

#define BAR   __builtin_amdgcn_s_barrier()
#define VM4   asm volatile("s_waitcnt vmcnt(4)" ::: "memory")
#define VM6   asm volatile("s_waitcnt vmcnt(6)" ::: "memory")

    f32x4 acc[8][4];
    #pragma unroll
    for (int i = 0; i < 8; ++i)
        #pragma unroll
        for (int j = 0; j < 4; ++j)
            acc[i][j] = (f32x4){0.f, 0.f, 0.f, 0.f};

    bf16x8 af[4][2], bfA[2][2], bfB[2][2];

    // prologue: t0 full (8) + t1 {B0,B1,A0} (6); VM6 retires t0; BAR; Q0 reads.
    STAGE_B(0, 0, 0);  STAGE_B(0, 1, 0);
    STAGE_A(0, 0, 0);  STAGE_A(0, 1, 0);
    STAGE_B(1, 0, 1);  STAGE_B(1, 1, 1);
    STAGE_A(1, 0, 1);
    VM6;  BAR;
    RD_A(0, 0);  RD_B(0, 0, bfA);        // af0(t0), bfA(t0)

    #pragma unroll 1
    for (int it = 0; it < NIT; ++it) {
        const int ta = 2 * it + 1;                            // <=15 always
        const int tb = (2 * it + 2 <= 15) ? 2 * it + 2 : 15;  // E2 (buf0)
        const int tc = (2 * it + 3 <= 15) ? 2 * it + 3 : 15;  // O2 (buf1)

        // p0: Q0(E)
        BAR;
        RD_B(0, 2, bfB);                 // bfB(E) — p0's MM doesn't use bfB
        MM(0, 0, bfA);
        STAGE_A(1, 1, ta);               // A1(O)
        // p1: Q1(E)
        BAR;
        MM(0, 2, bfB);
        RD_A(0, 4);                      // af1(E)
        STAGE_B(0, 0, tb);               // B0(E2)
        VM6;                             // retires B-pair(O) -> bfA(O)@p2 ok
        // p2: Q2(E)
        BAR;
        MM(4, 0, bfA);
        RD_B(1, 0, bfA);                 // bfA(O), 2-phase lead
        STAGE_B(0, 1, tb);               // B1(E2)
        VM4;                             // retires A-pair(O) -> af0(O)@p3 ok
        // p3: Q3(E)
        BAR;
        MM(4, 2, bfB);
        RD_A(1, 0);                      // af0(O)
        STAGE_A(0, 0, tb);               // A0(E2)
        // p4: Q0(O)
        BAR;
        RD_B(1, 2, bfB);                 // bfB(O) — p4's MM doesn't use bfB
        MM(0, 0, bfA);
        STAGE_A(0, 1, tb);               // A1(E2)
        // p5: Q1(O)
        BAR;
        MM(0, 2, bfB);
        RD_A(1, 4);                      // af1(O)
        STAGE_B(1, 0, tc);               // B0(O2)
        VM6;                             // retires B-pair(E2) -> bfA(E2)@p6 ok
        // p6: Q2(O)
        BAR;
        MM(4, 0, bfA);
        RD_B(0, 0, bfA);                 // bfA(E2), 2-phase lead
        STAGE_B(1, 1, tc);               // B1(O2)
        VM4;                             // retires A-pair(E2) -> af0(E2)@p7 ok
        // p7: Q3(O)
        BAR;
        MM(4, 2, bfB);
        RD_A(0, 0);                      // af0(E2)
        STAGE_A(1, 0, tc);               // A0(O2)
    }

    asm volatile("s_waitcnt vmcnt(0)" ::: "memory");   // drain tail dups

    // epilogue: C/D layout col = lane&15, row = (lane>>4)*4 + r
    const int crow = (lane >> 4) * 4;
    const int ccol = lane & 15;
    float bv4[4];
    #pragma unroll
    for (int ni = 0; ni < 4; ++ni)
        bv4[ni] = bias[n0 + wc * 64 + ni * 16 + ccol];
    #pragma unroll
    for (int mi = 0; mi < 8; ++mi) {
        #pragma unroll
        for (int r = 0; r < 4; ++r) {
            const size_t rowg = (size_t)(m0 + wr * 128 + mi * 16 + crow + r) * N;
            #pragma unroll
            for (int ni = 0; ni < 4; ++ni) {
                const int col = n0 + wc * 64 + ni * 16 + ccol;
                float v = acc[mi][ni][r] + bv4[ni];
                if constexpr (std::is_same<OutT, float>::value) {
                    C[rowg + col] = v;
                } else {
                    C[rowg + col] = f2b(v);
                }
            }
        }
    }
#undef GLD
#undef STAGE_A
#undef STAGE_B
#undef RD_A
#undef RD_B
#undef MM
#undef BAR
#undef VM4
#undef VM6
}

// ---------------- per-token head-mixing attention ----------------------
__global__ __launch_bounds__(256) void k_attn(
    const short* __restrict__ QKV, short* __restrict__ O)
{
    __shared__ short Ks[16][1032];
    __shared__ short Vs[16][1032];

    const int tid = threadIdx.x;
    const int tok0 = blockIdx.x * 16;

    for (int i = tid; i < 2048; i += 256) {
        int t = i >> 7;
        int j = i & 127;
        const size_t base = (size_t)(tok0 + t) * QKV_STRIDE;
        *reinterpret_cast<short8_t*>(&Ks[t][j * 8]) =
            *reinterpret_cast<const short8_t*>(&QKV[base + 1024 + j * 8]);
        *reinterpret_cast<short8_t*>(&Vs[t][j * 8]) =
            *reinterpret_cast<const short8_t*>(&QKV[base + 2048 + j * 8]);
    }
    __syncthreads();

    const int tl = tid >> 4;
    const int h  = tid & 15;

    float qf[64];
    const short* qp = QKV + (size_t)(tok0 + tl) * QKV_STRIDE + h * HD;
    #pragma unroll
    for (int i = 0; i < 8; ++i) {
        short8_t v = *reinterpret_cast<const short8_t*>(&qp[i * 8]);
        #pragma unroll
        for (int j = 0; j < 8; ++j) qf[i * 8 + j] = b2f(v[j]);
    }

    float s[16];
    #pragma unroll
    for (int g = 0; g < 16; ++g) {
        float a = 0.f;
        #pragma unroll
        for (int i = 0; i < 8; ++i) {
            short8_t kv = *reinterpret_cast<const short8_t*>(&Ks[tl][g * HD + i * 8]);
            #pragma unroll
            for (int j = 0; j < 8; ++j) a += qf[i * 8 + j] * b2f(kv[j]);
        }
        s[g] = a * 0.125f;
    }
    float mx = s[0];
    #pragma unroll
    for (int g = 1; g < 16; ++g) mx = fmaxf(mx, s[g]);
    float l = 0.f;
    #pragma unroll
    for (int g = 0; g < 16; ++g) { s[g] = __expf(s[g] - mx); l += s[g]; }
    const float inv = 1.f / l;
    #pragma unroll
    for (int g = 0; g < 16; ++g) s[g] *= inv;

    short* op = O + (size_t)(tok0 + tl) * E_DIM + h * HD;
    #pragma unroll
    for (int c = 0; c < 4; ++c) {
        float a[16];
        #pragma unroll
        for (int j = 0; j < 16; ++j) a[j] = 0.f;
        #pragma unroll
        for (int g = 0; g < 16; ++g) {
            short8_t v0 = *reinterpret_cast<const short8_t*>(&Vs[tl][g * HD + c * 16]);
            short8_t v1 = *reinterpret_cast<const short8_t*>(&Vs[tl][g * HD + c * 16 + 8]);
            #pragma unroll
            for (int j = 0; j < 8; ++j) {
                a[j]     += s[g] * b2f(v0[j]);
                a[8 + j] += s[g] * b2f(v1[j]);
            }
        }
        short8_t o0, o1;
        #pragma unroll
        for (int j = 0; j < 8; ++j) { o0[j] = f2b(a[j]); o1[j] = f2b(a[8 + j]); }
        *reinterpret_cast<short8_t*>(&op[c * 16])     = o0;
        *reinterpret_cast<short8_t*>(&op[c * 16 + 8]) = o1;
    }
}

extern "C" void kernel_launch(void* const* d_in, const int* in_sizes, int n_in,
                              void* d_out, int out_size, void* d_ws, size_t ws_size,
                              hipStream_t stream) {
    const float* x  = (const float*)d_in[0];
    const float* Wq = (const float*)d_in[1];
    const float* bq = (const float*)d_in[2];
    const float* Wk = (const float*)d_in[3];
    const float* bk = (const float*)d_in[4];
    const float* Wv = (const float*)d_in[5];
    const float* bv = (const float*)d_in[6];
    const float* Wo = (const float*)d_in[7];
    const float* bo = (const float*)d_in[8];
    float* out = (float*)d_out;

    const int T = in_sizes[0] / E_DIM;      // 32768 tokens
    char* ws = (char*)d_ws;
    const size_t SZ_X    = (size_t)T * E_DIM * 2;
    const size_t SZ_WQKV = (size_t)3 * E_DIM * E_DIM * 2;
    const size_t SZ_W    = (size_t)E_DIM * E_DIM * 2;
    const size_t SZ_B    = 3072 * sizeof(float) + 4096;

    short* xb    = (short*)(ws);
    short* Wqkvb = (short*)(ws + SZ_X);
    short* Wob   = (short*)(ws + SZ_X + SZ_WQKV);
    float* bqkv  = (float*)(ws + SZ_X + SZ_WQKV + SZ_W);
    short* QKVb  = (short*)(ws + SZ_X + SZ_WQKV + SZ_W + SZ_B);
    short* Ab    = xb;   // reuse x-bf16 buffer for attention output

    const int n4x = T * E_DIM / 4;          // 8M float4
    const int n4w = E_DIM * E_DIM / 4;      // 256K float4
    const int nprep = n4x + 4 * n4w + 768;
    k_prep<<<dim3((nprep + 255) / 256), dim3(256), 0, stream>>>(
        x, Wq, Wk, Wv, Wo, bq, bk, bv, xb, Wqkvb, Wob, bqkv, n4x, n4w);

    // fused QKV GEMM: [T][3072]
    k_gemm256<short><<<dim3((T / 256) * (QKV_STRIDE / 256)), dim3(512), 0, stream>>>(
        xb, Wqkvb, bqkv, QKVb, QKV_STRIDE / 256, QKV_STRIDE);

    k_attn<<<dim3(T / 16), dim3(256), 0, stream>>>(QKVb, Ab);

    // output GEMM: [T][1024] fp32
    k_gemm256<float><<<dim3((T / 256) * (E_DIM / 256)), dim3(512), 0, stream>>>(
        Ab, Wob, bo, out, E_DIM / 256, E_DIM);
}